// Round 3
// baseline (80.541 us; speedup 1.0000x reference)
//
#include <hip/hip_runtime.h>
#include <stdint.h>

#define SC 192      // coarse samples (128 + 64)
#define SF 128      // fine (importance) samples
#define NT 128      // threads per block = 2 waves

// LDS weight-image offsets (floats)
#define WD1   0     // 96  (3x32 row-major) -- DEAD after staging; overlaid by s_dv[32] at runtime
#define BD1   96    // 32
#define WD2   128   // 32
#define BD2   160   // 1
#define BC2   161   // 3
#define NV4   164   // 32 x float4: (bc1[n], Wc1[32][n], Wc1[33][n], Wc1[34][n])
#define W24   292   // 12 x uint4: compact Wc2 fp16 A-frags, idx = quad*3 + channel
#define SWTOT 420   // floats (105 float4s)

#define WS_FRAG_OFF 2048    // byte offset of Wc1 fp16 A-frags in d_ws
#define WS_NEED     4096

#define HSTRIDE 40  // ushort stride for H rows (80 B rows -> bank-friendly, 16B-aligned)
#define RGBS 4

using half8 = __attribute__((ext_vector_type(8))) _Float16;
using f32x4 = __attribute__((ext_vector_type(4))) float;

__device__ __forceinline__ float zlog_c(int t) {
  return (t < 128) ? (-1.0f + (float)t * 0.0078125f)
                   : ((float)(t - 128) * 0.015625f);
}
__device__ __forceinline__ float delta_c(int t) {
  if (t >= SC - 1) return 0.0f;
  return zlog_c(t + 1) - zlog_c(t);
}

__device__ __forceinline__ float fast_rcp(float x) { return __builtin_amdgcn_rcpf(x); }
__device__ __forceinline__ float fast_rsq(float x) { return __builtin_amdgcn_rsqf(x); }
__device__ __forceinline__ float exp10_f(float x) { return __expf(x * 2.30258509299f); }
__device__ __forceinline__ float softplus_f(float x) {
  return fmaxf(x, 0.0f) + __logf(1.0f + __expf(-fabsf(x)));
}

// fp16 helpers: pk2h = 1 HW instr (v_cvt_pkrtz_f16_f32); f2h = RTN scalar convert
__device__ __forceinline__ uint32_t pk2h(float a, float b) {
  auto p = __builtin_amdgcn_cvt_pkrtz(a, b);
  uint32_t u; __builtin_memcpy(&u, &p, 4); return u;
}
__device__ __forceinline__ unsigned short f2h(float f) {
  _Float16 h = (_Float16)f;
  unsigned short us; __builtin_memcpy(&us, &h, 2); return us;
}

__device__ __forceinline__ float4 ldsf4(const float* p) { return *(const float4*)p; }

// hidden-axis permutation for Wc1 A-frags: frag0 row i -> hidden 8*(i>>2)+(i&3),
// frag1 row i -> +4. Makes MFMA1's packed relu output land register-direct as
// MFMA2's B-frag (k = quad*8 + j = hidden), eliminating the LDS round-trip.
__device__ __forceinline__ int hperm(int i, int ntf) {
  return 8 * (i >> 2) + (i & 3) + ntf * 4;
}

// JAX threefry2x32 with key = (0, 42)
__device__ __forceinline__ void threefry2x32_k42(uint32_t& x0, uint32_t& x1) {
  const uint32_t ks0 = 0u, ks1 = 42u;
  const uint32_t ks2 = ks0 ^ ks1 ^ 0x1BD11BDAu;
  const uint32_t ks[3] = {ks0, ks1, ks2};
  const int rot[2][4] = {{13, 15, 26, 6}, {17, 29, 16, 24}};
  x0 += ks[0];
  x1 += ks[1];
#pragma unroll
  for (int i = 0; i < 5; ++i) {
#pragma unroll
    for (int j = 0; j < 4; ++j) {
      x0 += x1;
      const int r = rot[i & 1][j];
      x1 = (x1 << r) | (x1 >> (32 - r));
      x1 ^= x0;
    }
    x0 += ks[(i + 1) % 3];
    x1 += ks[(i + 2) % 3] + (uint32_t)(i + 1);
  }
}

__device__ __forceinline__ float wave_scan_mul(float v, int lane) {
#pragma unroll
  for (int d = 1; d < 64; d <<= 1) {
    float o = __shfl_up(v, d, 64);
    if (lane >= d) v *= o;
  }
  return v;
}
__device__ __forceinline__ float wave_scan_add(float v, int lane) {
#pragma unroll
  for (int d = 1; d < 64; d <<= 1) {
    float o = __shfl_up(v, d, 64);
    if (lane >= d) v += o;
  }
  return v;
}

// ---- pre-pack kernel: weight image + fp16 Wc1 A-frags (identical for all blocks) ----
__global__ __launch_bounds__(NT) void pack_weights(
    const float* __restrict__ Wd1, const float* __restrict__ bd1,
    const float* __restrict__ Wd2, const float* __restrict__ bd2,
    const float* __restrict__ Wc1, const float* __restrict__ bc1,
    const float* __restrict__ Wc2, const float* __restrict__ bc2,
    float* __restrict__ wsf) {
  const int t = threadIdx.x;
  for (int i = t; i < 96; i += NT) wsf[WD1 + i] = Wd1[i];
  for (int i = t; i < 32; i += NT) { wsf[BD1 + i] = bd1[i]; wsf[WD2 + i] = Wd2[i]; }
  if (t == 0) {
    wsf[BD2] = bd2[0];
    wsf[BC2 + 0] = bc2[0]; wsf[BC2 + 1] = bc2[1]; wsf[BC2 + 2] = bc2[2];
  }
  if (t < 32) {
    wsf[NV4 + t * 4 + 0] = bc1[t];
    wsf[NV4 + t * 4 + 1] = Wc1[32 * 32 + t];
    wsf[NV4 + t * 4 + 2] = Wc1[33 * 32 + t];
    wsf[NV4 + t * 4 + 3] = Wc1[34 * 32 + t];
  }
  // compact Wc2 fp16 A-frags for MFMA2 (16x16x32): A[m=channel][k=n]
  // entry idx = q*3 + m (q = k-quad, m = channel 0..2): 8 halves = uint4
  if (t < 12) {
    const int m = t % 3, q = t / 3;
    uint32_t hw[4];
#pragma unroll
    for (int j2 = 0; j2 < 4; ++j2) {
      const int k0 = q * 8 + j2 * 2;
      hw[j2] = (uint32_t)f2h(Wc2[k0 * 3 + m])
             | ((uint32_t)f2h(Wc2[(k0 + 1) * 3 + m]) << 16);
    }
    ((uint4*)(wsf + W24))[t] = make_uint4(hw[0], hw[1], hw[2], hw[3]);
  }
  // Wc1[0:32][:] fp16 A-frags (hidden-permuted): frag[lane*2 + nt];
  // A[m][k]: frag row i = lane&15 -> hidden hperm(i, nt); k = quad*8+j
  if (t < 64) {
    const int q_s = t >> 4;
    const int i = t & 15;
    uint4* frag = (uint4*)((char*)wsf + WS_FRAG_OFF);
#pragma unroll
    for (int nt = 0; nt < 2; ++nt) {
      const int n_s = hperm(i, nt);
      uint32_t hw[4];
#pragma unroll
      for (int j2 = 0; j2 < 4; ++j2) {
        const int k = q_s * 8 + j2 * 2;
        hw[j2] = (uint32_t)f2h(Wc1[k * 32 + n_s])
               | ((uint32_t)f2h(Wc1[(k + 1) * 32 + n_s]) << 16);
      }
      frag[t * 2 + nt] = make_uint4(hw[0], hw[1], hw[2], hw[3]);
    }
  }
}

template <bool USE_WS>
__global__ __launch_bounds__(NT) void nerf_fwd(
    const float* __restrict__ hh, const float* __restrict__ ww,
    const float* __restrict__ K, const float* __restrict__ E,
    const float* __restrict__ bg,
    const float* __restrict__ Wd1, const float* __restrict__ bd1,
    const float* __restrict__ Wd2, const float* __restrict__ bd2,
    const float* __restrict__ Wc1, const float* __restrict__ bc1,
    const float* __restrict__ Wc2, const float* __restrict__ bc2,
    const float* __restrict__ wsf,
    float* __restrict__ out, int n_rays) {
  const int ray = blockIdx.x;
  const int t = threadIdx.x;
  const int lane = t & 63;
  const int wv = t >> 6;   // 0 or 1
  const int quad = lane >> 4;

  __shared__ __align__(16) float sw[SWTOT];
  // per-ray factorized density-MLP coefficients: A = o@Wd1, B = d@Wd1
  __shared__ __align__(16) float s_A[32];
  __shared__ __align__(16) float s_B[32];
  // phase-union: coarse {s_w, s_cdf} then fine H (fp16)
  __shared__ __align__(16) unsigned char u_buf[SF * HSTRIDE * 2];  // 10240 B
  float* const s_w   = (float*)u_buf;
  float* const s_cdf = (float*)(u_buf + 768);
  unsigned short* const s_hf = (unsigned short*)u_buf;
  __shared__ float s_rgb[SF * RGBS];
  __shared__ float s_zlf[SF];
  __shared__ float s_tot[8];
  __shared__ float s_red[16];
  float* const s_dv = sw;   // overlay on dead WD1 region (never read after staging)

  // ---- stage weight image into LDS ----
  if constexpr (USE_WS) {
    const float4* wsrc = (const float4*)wsf;
    float4* sdst = (float4*)sw;
    for (int i = t; i < SWTOT / 4; i += NT) sdst[i] = wsrc[i];
  } else {
    for (int i = t; i < 96; i += NT) sw[WD1 + i] = Wd1[i];
    for (int i = t; i < 32; i += NT) { sw[BD1 + i] = bd1[i]; sw[WD2 + i] = Wd2[i]; }
    if (t == 0) {
      sw[BD2] = bd2[0];
      sw[BC2 + 0] = bc2[0]; sw[BC2 + 1] = bc2[1]; sw[BC2 + 2] = bc2[2];
    }
    if (t < 32) {
      sw[NV4 + t * 4 + 0] = bc1[t];
      sw[NV4 + t * 4 + 1] = Wc1[32 * 32 + t];
      sw[NV4 + t * 4 + 2] = Wc1[33 * 32 + t];
      sw[NV4 + t * 4 + 3] = Wc1[34 * 32 + t];
    }
    if (t < 12) {
      const int m = t % 3, q = t / 3;
      uint32_t hw[4];
#pragma unroll
      for (int j2 = 0; j2 < 4; ++j2) {
        const int k0 = q * 8 + j2 * 2;
        hw[j2] = (uint32_t)f2h(Wc2[k0 * 3 + m])
               | ((uint32_t)f2h(Wc2[(k0 + 1) * 3 + m]) << 16);
      }
      ((uint4*)(sw + W24))[t] = make_uint4(hw[0], hw[1], hw[2], hw[3]);
    }
  }

  // ---- ray setup (block-uniform) ----
  const float k00 = K[0], k01 = K[1], k02 = K[2];
  const float k10 = K[3], k11 = K[4], k12 = K[5];
  const float k20 = K[6], k21 = K[7], k22 = K[8];
  const float det = k00 * (k11 * k22 - k12 * k21)
                  - k01 * (k10 * k22 - k12 * k20)
                  + k02 * (k10 * k21 - k11 * k20);
  const float id = 1.0f / det;
  const float i00 =  (k11 * k22 - k12 * k21) * id;
  const float i01 = -(k01 * k22 - k02 * k21) * id;
  const float i02 =  (k01 * k12 - k02 * k11) * id;
  const float i10 = -(k10 * k22 - k12 * k20) * id;
  const float i11 =  (k00 * k22 - k02 * k20) * id;
  const float i12 = -(k00 * k12 - k02 * k10) * id;
  const float i20 =  (k10 * k21 - k11 * k20) * id;
  const float i21 = -(k00 * k21 - k01 * k20) * id;
  const float i22 =  (k00 * k11 - k01 * k10) * id;

  const float dwx = ww[ray] + 0.5f;
  const float dwy = hh[ray] + 0.5f;
  const float cx = i00 * dwx + i01 * dwy + i02;
  const float cy = i10 * dwx + i11 * dwy + i12;
  const float cz = i20 * dwx + i21 * dwy + i22;
  const float* Er = E + (size_t)ray * 16;
  const float ox = Er[3], oy = Er[7], oz = Er[11];
  const float dx = Er[0] * cx + Er[1] * cy + Er[2] * cz;
  const float dy = Er[4] * cx + Er[5] * cy + Er[6] * cz;
  const float dz = Er[8] * cx + Er[9] * cy + Er[10] * cz;
  const float dd = dx * dx + dy * dy + dz * dz;
  const float inv_nrm = fast_rsq(dd);
  const float ndx = dx * inv_nrm, ndy = dy * inv_nrm, ndz = dz * inv_nrm;
  // quadratic-expansion constants for dist^2 = |o + d z|^2
  const float oo  = ox * ox + oy * oy + oz * oz;
  const float od2 = 2.0f * (ox * dx + oy * dy + oz * dz);

  // A_n = o . Wd1[:,n], B_n = d . Wd1[:,n]  (per-ray, 32 threads, reads global Wd1)
  if (t < 32) {
    const float w0 = Wd1[t], w1 = Wd1[32 + t], w2 = Wd1[64 + t];
    s_A[t] = ox * w0 + oy * w1 + oz * w2;
    s_B[t] = dx * w0 + dy * w1 + dz * w2;
  }

  __syncthreads();   // weights + A/B staged

  // per-ray dv table: dv_n = bc1[n] + nd . Wc1[32:35][:,n]  (overlays dead WD1 region)
  if (t < 32) {
    const float4 nv = ldsf4(sw + NV4 + t * 4);
    s_dv[t] = nv.x + ndx * nv.y + ndy * nv.z + ndz * nv.w;
  }

  // ---- coarse pass: e0 = t (all threads); e1 = 128+t (wave 0 only, FUSED loop) ----
  // h_n = relu(ms * A_n + msz * B_n + b_n), ms = mip scale, msz = ms*z
  const float bd2v = sw[BD2];
  float a0, v0, a1e = 0.0f, v1e = 1.0f;
  {
    float ms0, msz0, ms1 = 0.f, msz1 = 0.f;
    {
      const float z = exp10_f(zlog_c(t));
      const float d2 = fmaf(z, fmaf(z, dd, od2), oo);
      const float r = fast_rsq(fmaxf(d2, 1.0f));
      ms0 = (2.0f - r) * r;
      msz0 = ms0 * z;
    }
    if (wv == 0) {
      const float z = exp10_f((float)t * 0.015625f);   // zlog_c(128+t)
      const float d2 = fmaf(z, fmaf(z, dd, od2), oo);
      const float r = fast_rsq(fmaxf(d2, 1.0f));
      ms1 = (2.0f - r) * r;
      msz1 = ms1 * z;
    }
    float acc0 = bd2v, acc1 = bd2v;
    if (wv == 0) {  // wave-uniform branch: fused 2-sample loop (coeffs loaded once)
#pragma unroll 2
      for (int c = 0; c < 8; ++c) {
        const int k4 = c * 4;
        const float4 A  = ldsf4(s_A + k4);
        const float4 B  = ldsf4(s_B + k4);
        const float4 b  = ldsf4(sw + BD1 + k4);
        const float4 wd = ldsf4(sw + WD2 + k4);
        float v;
        v = fmaf(msz0, B.x, fmaf(ms0, A.x, b.x)); acc0 += fmaxf(v, 0.0f) * wd.x;
        v = fmaf(msz0, B.y, fmaf(ms0, A.y, b.y)); acc0 += fmaxf(v, 0.0f) * wd.y;
        v = fmaf(msz0, B.z, fmaf(ms0, A.z, b.z)); acc0 += fmaxf(v, 0.0f) * wd.z;
        v = fmaf(msz0, B.w, fmaf(ms0, A.w, b.w)); acc0 += fmaxf(v, 0.0f) * wd.w;
        v = fmaf(msz1, B.x, fmaf(ms1, A.x, b.x)); acc1 += fmaxf(v, 0.0f) * wd.x;
        v = fmaf(msz1, B.y, fmaf(ms1, A.y, b.y)); acc1 += fmaxf(v, 0.0f) * wd.y;
        v = fmaf(msz1, B.z, fmaf(ms1, A.z, b.z)); acc1 += fmaxf(v, 0.0f) * wd.z;
        v = fmaf(msz1, B.w, fmaf(ms1, A.w, b.w)); acc1 += fmaxf(v, 0.0f) * wd.w;
      }
    } else {
#pragma unroll 2
      for (int c = 0; c < 8; ++c) {
        const int k4 = c * 4;
        const float4 A  = ldsf4(s_A + k4);
        const float4 B  = ldsf4(s_B + k4);
        const float4 b  = ldsf4(sw + BD1 + k4);
        const float4 wd = ldsf4(sw + WD2 + k4);
        float v;
        v = fmaf(msz0, B.x, fmaf(ms0, A.x, b.x)); acc0 += fmaxf(v, 0.0f) * wd.x;
        v = fmaf(msz0, B.y, fmaf(ms0, A.y, b.y)); acc0 += fmaxf(v, 0.0f) * wd.y;
        v = fmaf(msz0, B.z, fmaf(ms0, A.z, b.z)); acc0 += fmaxf(v, 0.0f) * wd.z;
        v = fmaf(msz0, B.w, fmaf(ms0, A.w, b.w)); acc0 += fmaxf(v, 0.0f) * wd.w;
      }
    }
    v0 = __expf(-softplus_f(acc0) * delta_c(t));
    a0 = 1.0f - v0;
    if (wv == 0) {
      v1e = __expf(-softplus_f(acc1) * delta_c(128 + t));
      a1e = 1.0f - v1e;
    }
  }

  // parallel cumprod of (1-alpha)
  float i0 = wave_scan_mul(v0, lane);
  float i1 = 1.0f;
  if (wv == 0) i1 = wave_scan_mul(v1e, lane);
  if (lane == 63) s_tot[wv] = i0;
  if (wv == 0 && lane == 63) s_tot[2] = i1;
  __syncthreads();
  {
    const float preC1 = s_tot[0];
    const float preC2 = s_tot[0] * s_tot[1];
    float e0x = __shfl_up(i0, 1, 64); if (lane == 0) e0x = 1.0f;
    s_w[t] = a0 * e0x * (wv ? preC1 : 1.0f);
    if (wv == 0) {
      float e1x = __shfl_up(i1, 1, 64); if (lane == 0) e1x = 1.0f;
      s_w[128 + t] = a1e * e1x * preC2;
    }
  }
  __syncthreads();

  // reweight
  float wre0, wre1 = 0.0f;
  {
    const float wm = (t > 0) ? s_w[t - 1] : 0.0f;
    const float w0 = s_w[t];
    const float wp = s_w[t + 1];
    wre0 = 0.5f * (fmaxf(wm, w0) + fmaxf(w0, wp)) + (0.02f / 192.0f);
    wre0 *= (t < 128) ? (128.0f / 192.0f) : (64.0f / 192.0f);
  }
  if (wv == 0) {
    const int e = 128 + t;
    const float wm = s_w[e - 1];
    const float w0 = s_w[e];
    const float wp = (e < SC - 1) ? s_w[e + 1] : 0.0f;
    wre1 = 0.5f * (fmaxf(wm, w0) + fmaxf(w0, wp)) + (0.02f / 192.0f);
    wre1 *= (64.0f / 192.0f);
  }

  // parallel cumsum -> normalized CDF
  float s0 = wave_scan_add(wre0, lane);
  float s1 = 0.0f;
  if (wv == 0) s1 = wave_scan_add(wre1, lane);
  if (lane == 63) s_tot[4 + wv] = s0;
  if (wv == 0 && lane == 63) s_tot[6] = s1;
  __syncthreads();
  {
    const float T0 = s_tot[4], T1 = s_tot[5], T2 = s_tot[6];
    const float inv_total = fast_rcp(T0 + T1 + T2);
    s_cdf[t] = (s0 + (wv ? T0 : 0.0f)) * inv_total;
    if (wv == 0) s_cdf[128 + t] = (s1 + T0 + T1) * inv_total;
  }
  __syncthreads();

  // ---- importance sampling ----
  float zlf, zf;
  {
    const uint32_t total = (uint32_t)n_rays * 128u;
    const uint32_t halfc = total >> 1;
    const uint32_t j = (uint32_t)ray * 128u + (uint32_t)t;
    uint32_t x0, x1;
    const bool first = (j < halfc);
    if (first) { x0 = j; x1 = j + halfc; } else { x0 = j - halfc; x1 = j; }
    threefry2x32_k42(x0, x1);
    const uint32_t bits = first ? x0 : x1;
    const float fr = __uint_as_float((bits >> 9) | 0x3f800000u) - 1.0f;

    float u = (float)t * 0.0078125f + fr * 0.0078125f;
    u = u * (s_cdf[190] - s_cdf[1]) + s_cdf[1];

    int lo = 0, hi = 189;
    while (lo < hi) {
      const int mid = (lo + hi) >> 1;
      if (s_cdf[1 + mid] <= u) lo = mid + 1; else hi = mid;
    }
    const int inds = lo + 1;
    const float cb = s_cdf[inds - 1], ca = s_cdf[inds];
    const float tt = (u - cb) * fast_rcp(ca - cb);
    const float zb = 0.5f * (zlog_c(inds - 1) + zlog_c(inds));
    const float za = 0.5f * (zlog_c(inds) + zlog_c(inds + 1));
    zlf = zb + (za - zb) * tt;
    s_zlf[t] = zlf;
    zf = exp10_f(zlf);
  }
  __syncthreads();   // last s_cdf read — union area now free for s_hf

  // ---- Wc1 A-frags (fp16, hidden-permuted) ----
  half8 Whi0, Whi1;
  if constexpr (USE_WS) {
    const uint4* frag = (const uint4*)((const char*)wsf + WS_FRAG_OFF);
    uint4 q0 = frag[lane * 2 + 0];
    uint4 q1 = frag[lane * 2 + 1];
    __builtin_memcpy(&Whi0, &q0, 16);
    __builtin_memcpy(&Whi1, &q1, 16);
  } else {
#pragma unroll
    for (int nt = 0; nt < 2; ++nt) {
      const int n_s = hperm(lane & 15, nt);
      uint32_t hw[4];
#pragma unroll
      for (int j2 = 0; j2 < 4; ++j2) {
        const int k = quad * 8 + j2 * 2;
        hw[j2] = (uint32_t)f2h(Wc1[k * 32 + n_s])
               | ((uint32_t)f2h(Wc1[(k + 1) * 32 + n_s]) << 16);
      }
      uint4 q = make_uint4(hw[0], hw[1], hw[2], hw[3]);
      if (nt == 0) __builtin_memcpy(&Whi0, &q, 16);
      else         __builtin_memcpy(&Whi1, &q, 16);
    }
  }

  // ---- fine density per-thread (factorized); h -> LDS as fp16 (HW pack) ----
  float sigf;
  {
    const float d2 = fmaf(zf, fmaf(zf, dd, od2), oo);
    const float r = fast_rsq(fmaxf(d2, 1.0f));
    const float msf = (2.0f - r) * r;
    const float mszf = msf * zf;
    float sig_acc = bd2v;
    uint4 tmp;
#pragma unroll
    for (int c = 0; c < 8; ++c) {
      const int k4 = c * 4;
      const float4 A  = ldsf4(s_A + k4);
      const float4 B  = ldsf4(s_B + k4);
      const float4 b  = ldsf4(sw + BD1 + k4);
      const float4 wd = ldsf4(sw + WD2 + k4);
      float h0 = fmaxf(fmaf(mszf, B.x, fmaf(msf, A.x, b.x)), 0.0f);
      float h1 = fmaxf(fmaf(mszf, B.y, fmaf(msf, A.y, b.y)), 0.0f);
      float h2 = fmaxf(fmaf(mszf, B.z, fmaf(msf, A.z, b.z)), 0.0f);
      float h3 = fmaxf(fmaf(mszf, B.w, fmaf(msf, A.w, b.w)), 0.0f);
      sig_acc += h0 * wd.x + h1 * wd.y + h2 * wd.z + h3 * wd.w;
      const uint32_t pA = pk2h(h0, h1), pB = pk2h(h2, h3);
      if ((c & 1) == 0) { tmp.x = pA; tmp.y = pB; }
      else {
        tmp.z = pA; tmp.w = pB;
        *(uint4*)(s_hf + t * HSTRIDE + (c >> 1) * 8) = tmp;
      }
    }
    sigf = softplus_f(sig_acc);
  }
  // NO barrier: each wave's MFMA reads only its own 64 rows (same-wave LDS RAW,
  // ordered by compiler lgkmcnt); s_zlf/s_cdf visibility covered by prior barrier.

  // ---- fine color via MFMA, both layers, register-direct ----
  // layer1 (hidden-permuted A): acc{0,1} C row i = hidden hperm(i,{0,1}), col = sample.
  // av = relu(acc + dv) packed -> EXACTLY MFMA2's B-frag (k=quad*8+j = hidden, col=sample).
  // layer2: rgb_pre[3 x 16] = Wc2^T . av  (A rows 0..2 = channels)
  {
    const float4 dv0 = ldsf4(s_dv + quad * 8);       // hidden 8q..8q+3
    const float4 dv1 = ldsf4(s_dv + quad * 8 + 4);   // hidden 8q+4..8q+7
    const int m15 = lane & 15;
    uint4 qf = ((const uint4*)(sw + W24))[quad * 3 + (m15 < 3 ? m15 : 0)];
    if (m15 >= 3) qf = make_uint4(0u, 0u, 0u, 0u);
    half8 W2f; __builtin_memcpy(&W2f, &qf, 16);
    const float bc2x = sw[BC2 + 0], bc2y = sw[BC2 + 1], bc2z = sw[BC2 + 2];

#pragma unroll
    for (int mt = 0; mt < 4; ++mt) {
      const int scol = wv * 64 + mt * 16 + m15;
      const half8 Hf = *(const half8*)(s_hf + scol * HSTRIDE + quad * 8);

      f32x4 acc0 = {0.f, 0.f, 0.f, 0.f}, acc1 = {0.f, 0.f, 0.f, 0.f};
      acc0 = __builtin_amdgcn_mfma_f32_16x16x32_f16(Whi0, Hf, acc0, 0, 0, 0);
      acc1 = __builtin_amdgcn_mfma_f32_16x16x32_f16(Whi1, Hf, acc1, 0, 0, 0);

      uint4 bw;
      bw.x = pk2h(fmaxf(acc0[0] + dv0.x, 0.0f), fmaxf(acc0[1] + dv0.y, 0.0f));
      bw.y = pk2h(fmaxf(acc0[2] + dv0.z, 0.0f), fmaxf(acc0[3] + dv0.w, 0.0f));
      bw.z = pk2h(fmaxf(acc1[0] + dv1.x, 0.0f), fmaxf(acc1[1] + dv1.y, 0.0f));
      bw.w = pk2h(fmaxf(acc1[2] + dv1.z, 0.0f), fmaxf(acc1[3] + dv1.w, 0.0f));
      half8 Bav; __builtin_memcpy(&Bav, &bw, 16);

      f32x4 acc2 = {0.f, 0.f, 0.f, 0.f};
      acc2 = __builtin_amdgcn_mfma_f32_16x16x32_f16(W2f, Bav, acc2, 0, 0, 0);
      if (quad == 0) {
        float4 px;
        px.x = fast_rcp(1.0f + __expf(-(acc2[0] + bc2x)));
        px.y = fast_rcp(1.0f + __expf(-(acc2[1] + bc2y)));
        px.z = fast_rcp(1.0f + __expf(-(acc2[2] + bc2z)));
        px.w = 0.0f;
        *(float4*)(s_rgb + scol * RGBS) = px;
      }
    }
  }

  // ---- fine alpha + parallel cumprod over 128 ----
  const float deltaf = (t < SF - 1) ? (s_zlf[t + 1] - zlf) : 0.0f;
  const float vf = __expf(-sigf * deltaf);
  const float af = 1.0f - vf;
  float fi = wave_scan_mul(vf, lane);
  if (lane == 63) s_tot[wv] = fi;
  __syncthreads();   // makes s_tot and s_rgb visible cross-wave
  float efx = __shfl_up(fi, 1, 64); if (lane == 0) efx = 1.0f;
  const float wf = af * efx * (wv ? s_tot[0] : 1.0f);

  // ---- outputs ----
  float* o_img = out;
  float* o_w   = out + (size_t)n_rays * 3;
  float* o_z   = out + (size_t)n_rays * (3 + 128);
  float* o_inv = out + (size_t)n_rays * (3 + 256);

  o_w[(size_t)ray * 128 + t] = wf;
  o_z[(size_t)ray * 128 + t] = (zlf + 1.0f) * 0.5f;

  const float4 rgbv = ldsf4(s_rgb + t * RGBS);
  float r0 = wf * rgbv.x;
  float r1 = wf * rgbv.y;
  float r2 = wf * rgbv.z;
  float r3 = wf, r4 = wf * fast_rcp(zf);
#pragma unroll
  for (int d = 32; d > 0; d >>= 1) {
    r0 += __shfl_down(r0, d, 64);
    r1 += __shfl_down(r1, d, 64);
    r2 += __shfl_down(r2, d, 64);
    r3 += __shfl_down(r3, d, 64);
    r4 += __shfl_down(r4, d, 64);
  }
  if (lane == 0) {
    float* p = &s_red[wv * 5];
    p[0] = r0; p[1] = r1; p[2] = r2; p[3] = r3; p[4] = r4;
  }
  __syncthreads();
  if (t == 0) {
    const float accw = s_red[3] + s_red[8];
    const float bgw = 1.0f - accw;
    o_img[(size_t)ray * 3 + 0] = (s_red[0] + s_red[5]) + bgw * bg[0];
    o_img[(size_t)ray * 3 + 1] = (s_red[1] + s_red[6]) + bgw * bg[1];
    o_img[(size_t)ray * 3 + 2] = (s_red[2] + s_red[7]) + bgw * bg[2];
    o_inv[ray] = s_red[4] + s_red[9];
  }
}

extern "C" void kernel_launch(void* const* d_in, const int* in_sizes, int n_in,
                              void* d_out, int out_size, void* d_ws, size_t ws_size,
                              hipStream_t stream) {
  const float* h   = (const float*)d_in[1];
  const float* w   = (const float*)d_in[2];
  const float* K   = (const float*)d_in[3];
  const float* E   = (const float*)d_in[4];
  const float* bg  = (const float*)d_in[5];
  const float* Wd1 = (const float*)d_in[6];
  const float* bd1 = (const float*)d_in[7];
  const float* Wd2 = (const float*)d_in[8];
  const float* bd2 = (const float*)d_in[9];
  const float* Wc1 = (const float*)d_in[10];
  const float* bc1 = (const float*)d_in[11];
  const float* Wc2 = (const float*)d_in[12];
  const float* bc2 = (const float*)d_in[13];
  const int n_rays = in_sizes[1];
  float* wsf = (float*)d_ws;

  if (ws_size >= WS_NEED) {
    pack_weights<<<1, NT, 0, stream>>>(Wd1, bd1, Wd2, bd2, Wc1, bc1, Wc2, bc2, wsf);
    nerf_fwd<true><<<n_rays, NT, 0, stream>>>(h, w, K, E, bg, Wd1, bd1, Wd2, bd2,
                                              Wc1, bc1, Wc2, bc2, wsf,
                                              (float*)d_out, n_rays);
  } else {
    nerf_fwd<false><<<n_rays, NT, 0, stream>>>(h, w, K, E, bg, Wd1, bd1, Wd2, bd2,
                                               Wc1, bc1, Wc2, bc2, nullptr,
                                               (float*)d_out, n_rays);
  }
}

// Round 4
// 66.881 us; speedup vs baseline: 1.2042x; 1.2042x over previous
//
#include <hip/hip_runtime.h>
#include <stdint.h>

#define SC 192      // coarse samples (128 + 64)
#define SF 128      // fine (importance) samples
#define NT 128      // threads per block = 2 waves

// LDS weight-image offsets (floats)
#define WD1   0     // 96  (3x32 row-major) -- DEAD after staging; overlaid by s_dv[32] at runtime
#define BD1   96    // 32
#define WD2   128   // 32
#define BD2   160   // 1
#define BC2   161   // 3
#define NV4   164   // 32 x float4: (bc1[n], Wc1[32][n], Wc1[33][n], Wc1[34][n])
#define W24   292   // 12 x uint4: compact Wc2 fp16 A-frags, idx = quad*3 + channel
#define SWTOT 420   // floats (105 float4s)

#define WS_FRAG_OFF 2048    // byte offset of Wc1 fp16 A-frags in d_ws
#define WS_NEED     4096

#define RGBS 4

using half8 = __attribute__((ext_vector_type(8))) _Float16;
using f32x4 = __attribute__((ext_vector_type(4))) float;

__device__ __forceinline__ float zlog_c(int t) {
  return (t < 128) ? (-1.0f + (float)t * 0.0078125f)
                   : ((float)(t - 128) * 0.015625f);
}
__device__ __forceinline__ float delta_c(int t) {
  if (t >= SC - 1) return 0.0f;
  return zlog_c(t + 1) - zlog_c(t);
}

__device__ __forceinline__ float fast_rcp(float x) { return __builtin_amdgcn_rcpf(x); }
__device__ __forceinline__ float fast_rsq(float x) { return __builtin_amdgcn_rsqf(x); }
__device__ __forceinline__ float exp10_f(float x) { return __expf(x * 2.30258509299f); }
__device__ __forceinline__ float softplus_f(float x) {
  return fmaxf(x, 0.0f) + __logf(1.0f + __expf(-fabsf(x)));
}

// fp16 helpers: pk2h = 1 HW instr (v_cvt_pkrtz_f16_f32); f2h = RTN scalar convert
__device__ __forceinline__ uint32_t pk2h(float a, float b) {
  auto p = __builtin_amdgcn_cvt_pkrtz(a, b);
  uint32_t u; __builtin_memcpy(&u, &p, 4); return u;
}
__device__ __forceinline__ unsigned short f2h(float f) {
  _Float16 h = (_Float16)f;
  unsigned short us; __builtin_memcpy(&us, &h, 2); return us;
}

__device__ __forceinline__ float4 ldsf4(const float* p) { return *(const float4*)p; }

// hidden-axis permutation for MFMA A-frags: frag0 row i -> hidden 8*(i>>2)+(i&3),
// frag1 row i -> +4. Then C rows (row = quad*4+reg) map to hidden 8*quad+reg(+4),
// so relu-packed C output lands register-direct as the NEXT MFMA's B-frag
// (k = quad*8 + j = true hidden index). Used for density->sigma/color1 and
// color1->color2 chains. No LDS round-trips.
__device__ __forceinline__ int hperm(int i, int ntf) {
  return 8 * (i >> 2) + (i & 3) + ntf * 4;
}

// JAX threefry2x32 with key = (0, 42)
__device__ __forceinline__ void threefry2x32_k42(uint32_t& x0, uint32_t& x1) {
  const uint32_t ks0 = 0u, ks1 = 42u;
  const uint32_t ks2 = ks0 ^ ks1 ^ 0x1BD11BDAu;
  const uint32_t ks[3] = {ks0, ks1, ks2};
  const int rot[2][4] = {{13, 15, 26, 6}, {17, 29, 16, 24}};
  x0 += ks[0];
  x1 += ks[1];
#pragma unroll
  for (int i = 0; i < 5; ++i) {
#pragma unroll
    for (int j = 0; j < 4; ++j) {
      x0 += x1;
      const int r = rot[i & 1][j];
      x1 = (x1 << r) | (x1 >> (32 - r));
      x1 ^= x0;
    }
    x0 += ks[(i + 1) % 3];
    x1 += ks[(i + 2) % 3] + (uint32_t)(i + 1);
  }
}

__device__ __forceinline__ float wave_scan_mul(float v, int lane) {
#pragma unroll
  for (int d = 1; d < 64; d <<= 1) {
    float o = __shfl_up(v, d, 64);
    if (lane >= d) v *= o;
  }
  return v;
}
__device__ __forceinline__ float wave_scan_add(float v, int lane) {
#pragma unroll
  for (int d = 1; d < 64; d <<= 1) {
    float o = __shfl_up(v, d, 64);
    if (lane >= d) v += o;
  }
  return v;
}

// ---- pre-pack kernel: weight image + fp16 Wc1 A-frags (identical for all blocks) ----
__global__ __launch_bounds__(NT) void pack_weights(
    const float* __restrict__ Wd1, const float* __restrict__ bd1,
    const float* __restrict__ Wd2, const float* __restrict__ bd2,
    const float* __restrict__ Wc1, const float* __restrict__ bc1,
    const float* __restrict__ Wc2, const float* __restrict__ bc2,
    float* __restrict__ wsf) {
  const int t = threadIdx.x;
  for (int i = t; i < 96; i += NT) wsf[WD1 + i] = Wd1[i];
  for (int i = t; i < 32; i += NT) { wsf[BD1 + i] = bd1[i]; wsf[WD2 + i] = Wd2[i]; }
  if (t == 0) {
    wsf[BD2] = bd2[0];
    wsf[BC2 + 0] = bc2[0]; wsf[BC2 + 1] = bc2[1]; wsf[BC2 + 2] = bc2[2];
  }
  if (t < 32) {
    wsf[NV4 + t * 4 + 0] = bc1[t];
    wsf[NV4 + t * 4 + 1] = Wc1[32 * 32 + t];
    wsf[NV4 + t * 4 + 2] = Wc1[33 * 32 + t];
    wsf[NV4 + t * 4 + 3] = Wc1[34 * 32 + t];
  }
  // compact Wc2 fp16 A-frags for MFMA2 (16x16x32): A[m=channel][k=n]
  // entry idx = q*3 + m (q = k-quad, m = channel 0..2): 8 halves = uint4
  if (t < 12) {
    const int m = t % 3, q = t / 3;
    uint32_t hw[4];
#pragma unroll
    for (int j2 = 0; j2 < 4; ++j2) {
      const int k0 = q * 8 + j2 * 2;
      hw[j2] = (uint32_t)f2h(Wc2[k0 * 3 + m])
             | ((uint32_t)f2h(Wc2[(k0 + 1) * 3 + m]) << 16);
    }
    ((uint4*)(wsf + W24))[t] = make_uint4(hw[0], hw[1], hw[2], hw[3]);
  }
  // Wc1[0:32][:] fp16 A-frags (hidden-permuted): frag[lane*2 + nt];
  // A[m][k]: frag row i = lane&15 -> hidden hperm(i, nt); k = quad*8+j
  if (t < 64) {
    const int q_s = t >> 4;
    const int i = t & 15;
    uint4* frag = (uint4*)((char*)wsf + WS_FRAG_OFF);
#pragma unroll
    for (int nt = 0; nt < 2; ++nt) {
      const int n_s = hperm(i, nt);
      uint32_t hw[4];
#pragma unroll
      for (int j2 = 0; j2 < 4; ++j2) {
        const int k = q_s * 8 + j2 * 2;
        hw[j2] = (uint32_t)f2h(Wc1[k * 32 + n_s])
               | ((uint32_t)f2h(Wc1[(k + 1) * 32 + n_s]) << 16);
      }
      frag[t * 2 + nt] = make_uint4(hw[0], hw[1], hw[2], hw[3]);
    }
  }
}

template <bool USE_WS>
__global__ __launch_bounds__(NT, 8) void nerf_fwd(
    const float* __restrict__ hh, const float* __restrict__ ww,
    const float* __restrict__ K, const float* __restrict__ E,
    const float* __restrict__ bg,
    const float* __restrict__ Wd1, const float* __restrict__ bd1,
    const float* __restrict__ Wd2, const float* __restrict__ bd2,
    const float* __restrict__ Wc1, const float* __restrict__ bc1,
    const float* __restrict__ Wc2, const float* __restrict__ bc2,
    const float* __restrict__ wsf,
    float* __restrict__ out, int n_rays) {
  const int ray = blockIdx.x;
  const int t = threadIdx.x;
  const int lane = t & 63;
  const int wv = t >> 6;   // 0 or 1
  const int quad = lane >> 4;
  const int m15 = lane & 15;

  __shared__ __align__(16) float sw[SWTOT];
  // per-ray factorized density-MLP coefficients: A = o@Wd1, B = d@Wd1
  __shared__ __align__(16) float s_A[32];
  __shared__ __align__(16) float s_B[32];
  // phase-union: coarse {s_w[192], s_cdf[192]} then fine {s_mm[128], s_sig[128], s_rgb[512]}
  __shared__ __align__(16) unsigned char u_buf[3072];
  float*    const s_w   = (float*)u_buf;                 // coarse
  float*    const s_cdf = (float*)(u_buf + 768);         // coarse
  uint32_t* const s_mm  = (uint32_t*)u_buf;              // fine: packed (ms,msz) fp16
  float*    const s_sig = (float*)(u_buf + 512);         // fine: sigma pre-softplus
  float*    const s_rgb = (float*)(u_buf + 1024);        // fine: rgb out (RGBS stride)
  __shared__ float s_zlf[SF];
  __shared__ float s_tot[8];
  __shared__ float s_red[16];
  float* const s_dv = sw;   // overlay on dead WD1 region (never read after staging)

  // ---- stage weight image into LDS ----
  if constexpr (USE_WS) {
    const float4* wsrc = (const float4*)wsf;
    float4* sdst = (float4*)sw;
    for (int i = t; i < SWTOT / 4; i += NT) sdst[i] = wsrc[i];
  } else {
    for (int i = t; i < 96; i += NT) sw[WD1 + i] = Wd1[i];
    for (int i = t; i < 32; i += NT) { sw[BD1 + i] = bd1[i]; sw[WD2 + i] = Wd2[i]; }
    if (t == 0) {
      sw[BD2] = bd2[0];
      sw[BC2 + 0] = bc2[0]; sw[BC2 + 1] = bc2[1]; sw[BC2 + 2] = bc2[2];
    }
    if (t < 32) {
      sw[NV4 + t * 4 + 0] = bc1[t];
      sw[NV4 + t * 4 + 1] = Wc1[32 * 32 + t];
      sw[NV4 + t * 4 + 2] = Wc1[33 * 32 + t];
      sw[NV4 + t * 4 + 3] = Wc1[34 * 32 + t];
    }
    if (t < 12) {
      const int m = t % 3, q = t / 3;
      uint32_t hw[4];
#pragma unroll
      for (int j2 = 0; j2 < 4; ++j2) {
        const int k0 = q * 8 + j2 * 2;
        hw[j2] = (uint32_t)f2h(Wc2[k0 * 3 + m])
               | ((uint32_t)f2h(Wc2[(k0 + 1) * 3 + m]) << 16);
      }
      ((uint4*)(sw + W24))[t] = make_uint4(hw[0], hw[1], hw[2], hw[3]);
    }
  }

  // ---- ray setup (block-uniform; mostly scalarized by compiler) ----
  const float k00 = K[0], k01 = K[1], k02 = K[2];
  const float k10 = K[3], k11 = K[4], k12 = K[5];
  const float k20 = K[6], k21 = K[7], k22 = K[8];
  const float det = k00 * (k11 * k22 - k12 * k21)
                  - k01 * (k10 * k22 - k12 * k20)
                  + k02 * (k10 * k21 - k11 * k20);
  const float id = 1.0f / det;
  const float i00 =  (k11 * k22 - k12 * k21) * id;
  const float i01 = -(k01 * k22 - k02 * k21) * id;
  const float i02 =  (k01 * k12 - k02 * k11) * id;
  const float i10 = -(k10 * k22 - k12 * k20) * id;
  const float i11 =  (k00 * k22 - k02 * k20) * id;
  const float i12 = -(k00 * k12 - k02 * k10) * id;
  const float i20 =  (k10 * k21 - k11 * k20) * id;
  const float i21 = -(k00 * k21 - k01 * k20) * id;
  const float i22 =  (k00 * k11 - k01 * k10) * id;

  const float dwx = ww[ray] + 0.5f;
  const float dwy = hh[ray] + 0.5f;
  const float cx = i00 * dwx + i01 * dwy + i02;
  const float cy = i10 * dwx + i11 * dwy + i12;
  const float cz = i20 * dwx + i21 * dwy + i22;
  const float* Er = E + (size_t)ray * 16;
  const float ox = Er[3], oy = Er[7], oz = Er[11];
  const float dx = Er[0] * cx + Er[1] * cy + Er[2] * cz;
  const float dy = Er[4] * cx + Er[5] * cy + Er[6] * cz;
  const float dz = Er[8] * cx + Er[9] * cy + Er[10] * cz;
  const float dd = dx * dx + dy * dy + dz * dz;
  const float inv_nrm = fast_rsq(dd);
  const float ndx = dx * inv_nrm, ndy = dy * inv_nrm, ndz = dz * inv_nrm;
  // quadratic-expansion constants for dist^2 = |o + d z|^2
  const float oo  = ox * ox + oy * oy + oz * oz;
  const float od2 = 2.0f * (ox * dx + oy * dy + oz * dz);

  // A_n = o . Wd1[:,n], B_n = d . Wd1[:,n]  (per-ray, 32 threads, reads global Wd1)
  if (t < 32) {
    const float w0 = Wd1[t], w1 = Wd1[32 + t], w2 = Wd1[64 + t];
    s_A[t] = ox * w0 + oy * w1 + oz * w2;
    s_B[t] = dx * w0 + dy * w1 + dz * w2;
  }

  __syncthreads();   // weights + A/B staged

  // per-ray dv table: dv_n = bc1[n] + nd . Wc1[32:35][:,n]  (overlays dead WD1 region)
  if (t < 32) {
    const float4 nv = ldsf4(sw + NV4 + t * 4);
    s_dv[t] = nv.x + ndx * nv.y + ndy * nv.z + ndz * nv.w;
  }

  // ---- coarse pass: e0 = t (all threads); e1 = 128+t (wave 0 only, FUSED loop) ----
  // h_n = relu(ms * A_n + msz * B_n + b_n), ms = mip scale, msz = ms*z
  // KEPT IN EXACT F32 FORM: this path determines the cdf / binary-search indices
  // (sampling positions) -- fp16 perturbation here risks discrete index jumps.
  const float bd2v = sw[BD2];
  float a0, v0, a1e = 0.0f, v1e = 1.0f;
  {
    float ms0, msz0, ms1 = 0.f, msz1 = 0.f;
    {
      const float z = exp10_f(zlog_c(t));
      const float d2 = fmaf(z, fmaf(z, dd, od2), oo);
      const float r = fast_rsq(fmaxf(d2, 1.0f));
      ms0 = (2.0f - r) * r;
      msz0 = ms0 * z;
    }
    if (wv == 0) {
      const float z = exp10_f((float)t * 0.015625f);   // zlog_c(128+t)
      const float d2 = fmaf(z, fmaf(z, dd, od2), oo);
      const float r = fast_rsq(fmaxf(d2, 1.0f));
      ms1 = (2.0f - r) * r;
      msz1 = ms1 * z;
    }
    float acc0 = bd2v, acc1 = bd2v;
    if (wv == 0) {  // wave-uniform branch: fused 2-sample loop (coeffs loaded once)
#pragma unroll 2
      for (int c = 0; c < 8; ++c) {
        const int k4 = c * 4;
        const float4 A  = ldsf4(s_A + k4);
        const float4 B  = ldsf4(s_B + k4);
        const float4 b  = ldsf4(sw + BD1 + k4);
        const float4 wd = ldsf4(sw + WD2 + k4);
        float v;
        v = fmaf(msz0, B.x, fmaf(ms0, A.x, b.x)); acc0 += fmaxf(v, 0.0f) * wd.x;
        v = fmaf(msz0, B.y, fmaf(ms0, A.y, b.y)); acc0 += fmaxf(v, 0.0f) * wd.y;
        v = fmaf(msz0, B.z, fmaf(ms0, A.z, b.z)); acc0 += fmaxf(v, 0.0f) * wd.z;
        v = fmaf(msz0, B.w, fmaf(ms0, A.w, b.w)); acc0 += fmaxf(v, 0.0f) * wd.w;
        v = fmaf(msz1, B.x, fmaf(ms1, A.x, b.x)); acc1 += fmaxf(v, 0.0f) * wd.x;
        v = fmaf(msz1, B.y, fmaf(ms1, A.y, b.y)); acc1 += fmaxf(v, 0.0f) * wd.y;
        v = fmaf(msz1, B.z, fmaf(ms1, A.z, b.z)); acc1 += fmaxf(v, 0.0f) * wd.z;
        v = fmaf(msz1, B.w, fmaf(ms1, A.w, b.w)); acc1 += fmaxf(v, 0.0f) * wd.w;
      }
    } else {
#pragma unroll 2
      for (int c = 0; c < 8; ++c) {
        const int k4 = c * 4;
        const float4 A  = ldsf4(s_A + k4);
        const float4 B  = ldsf4(s_B + k4);
        const float4 b  = ldsf4(sw + BD1 + k4);
        const float4 wd = ldsf4(sw + WD2 + k4);
        float v;
        v = fmaf(msz0, B.x, fmaf(ms0, A.x, b.x)); acc0 += fmaxf(v, 0.0f) * wd.x;
        v = fmaf(msz0, B.y, fmaf(ms0, A.y, b.y)); acc0 += fmaxf(v, 0.0f) * wd.y;
        v = fmaf(msz0, B.z, fmaf(ms0, A.z, b.z)); acc0 += fmaxf(v, 0.0f) * wd.z;
        v = fmaf(msz0, B.w, fmaf(ms0, A.w, b.w)); acc0 += fmaxf(v, 0.0f) * wd.w;
      }
    }
    v0 = __expf(-softplus_f(acc0) * delta_c(t));
    a0 = 1.0f - v0;
    if (wv == 0) {
      v1e = __expf(-softplus_f(acc1) * delta_c(128 + t));
      a1e = 1.0f - v1e;
    }
  }

  // parallel cumprod of (1-alpha)
  float i0 = wave_scan_mul(v0, lane);
  float i1 = 1.0f;
  if (wv == 0) i1 = wave_scan_mul(v1e, lane);
  if (lane == 63) s_tot[wv] = i0;
  if (wv == 0 && lane == 63) s_tot[2] = i1;
  __syncthreads();
  {
    const float preC1 = s_tot[0];
    const float preC2 = s_tot[0] * s_tot[1];
    float e0x = __shfl_up(i0, 1, 64); if (lane == 0) e0x = 1.0f;
    s_w[t] = a0 * e0x * (wv ? preC1 : 1.0f);
    if (wv == 0) {
      float e1x = __shfl_up(i1, 1, 64); if (lane == 0) e1x = 1.0f;
      s_w[128 + t] = a1e * e1x * preC2;
    }
  }
  __syncthreads();

  // reweight
  float wre0, wre1 = 0.0f;
  {
    const float wm = (t > 0) ? s_w[t - 1] : 0.0f;
    const float w0 = s_w[t];
    const float wp = s_w[t + 1];
    wre0 = 0.5f * (fmaxf(wm, w0) + fmaxf(w0, wp)) + (0.02f / 192.0f);
    wre0 *= (t < 128) ? (128.0f / 192.0f) : (64.0f / 192.0f);
  }
  if (wv == 0) {
    const int e = 128 + t;
    const float wm = s_w[e - 1];
    const float w0 = s_w[e];
    const float wp = (e < SC - 1) ? s_w[e + 1] : 0.0f;
    wre1 = 0.5f * (fmaxf(wm, w0) + fmaxf(w0, wp)) + (0.02f / 192.0f);
    wre1 *= (64.0f / 192.0f);
  }

  // parallel cumsum -> normalized CDF
  float s0 = wave_scan_add(wre0, lane);
  float s1 = 0.0f;
  if (wv == 0) s1 = wave_scan_add(wre1, lane);
  if (lane == 63) s_tot[4 + wv] = s0;
  if (wv == 0 && lane == 63) s_tot[6] = s1;
  __syncthreads();
  {
    const float T0 = s_tot[4], T1 = s_tot[5], T2 = s_tot[6];
    const float inv_total = fast_rcp(T0 + T1 + T2);
    s_cdf[t] = (s0 + (wv ? T0 : 0.0f)) * inv_total;
    if (wv == 0) s_cdf[128 + t] = (s1 + T0 + T1) * inv_total;
  }
  __syncthreads();

  // ---- importance sampling ----
  float zlf, zf;
  {
    const uint32_t total = (uint32_t)n_rays * 128u;
    const uint32_t halfc = total >> 1;
    const uint32_t j = (uint32_t)ray * 128u + (uint32_t)t;
    uint32_t x0, x1;
    const bool first = (j < halfc);
    if (first) { x0 = j; x1 = j + halfc; } else { x0 = j - halfc; x1 = j; }
    threefry2x32_k42(x0, x1);
    const uint32_t bits = first ? x0 : x1;
    const float fr = __uint_as_float((bits >> 9) | 0x3f800000u) - 1.0f;

    float u = (float)t * 0.0078125f + fr * 0.0078125f;
    u = u * (s_cdf[190] - s_cdf[1]) + s_cdf[1];

    int lo = 0, hi = 189;
    while (lo < hi) {
      const int mid = (lo + hi) >> 1;
      if (s_cdf[1 + mid] <= u) lo = mid + 1; else hi = mid;
    }
    const int inds = lo + 1;
    const float cb = s_cdf[inds - 1], ca = s_cdf[inds];
    const float tt = (u - cb) * fast_rcp(ca - cb);
    const float zb = 0.5f * (zlog_c(inds - 1) + zlog_c(inds));
    const float za = 0.5f * (zlog_c(inds) + zlog_c(inds + 1));
    zlf = zb + (za - zb) * tt;
    s_zlf[t] = zlf;
    zf = exp10_f(zlf);
  }
  __syncthreads();   // last s_cdf read — union area now free for s_mm/s_sig/s_rgb

  // ---- fine phase, pass 1: density via MFMA ----
  // input per sample = (ms, msz, 1); h = relu([A;B;b] @ (ms,msz,1)); sigma = wd.h
  // All LDS traffic below is same-wave (wave wv touches only samples wv*64..+63).
  {
    const float d2 = fmaf(zf, fmaf(zf, dd, od2), oo);
    const float r = fast_rsq(fmaxf(d2, 1.0f));
    const float msf = (2.0f - r) * r;
    s_mm[t] = pk2h(msf, msf * zf);
  }

  uint4 BhS0, BhS1, BhS2, BhS3;   // per-group packed h (fp16 B-frags), pass1 -> pass2
  {
    // per-ray density A-frags (hperm rows) + Wd2 row-frag, built once per wave
    const bool q0 = (quad == 0);
    const int ma = hperm(m15, 0), mb = hperm(m15, 1);
    uint4 fa, fb, fd;
    fa.x = q0 ? pk2h(s_A[ma], s_B[ma]) : 0u;
    fa.y = q0 ? (uint32_t)f2h(sw[BD1 + ma]) : 0u;
    fa.z = 0u; fa.w = 0u;
    fb.x = q0 ? pk2h(s_A[mb], s_B[mb]) : 0u;
    fb.y = q0 ? (uint32_t)f2h(sw[BD1 + mb]) : 0u;
    fb.z = 0u; fb.w = 0u;
    const bool r0 = (m15 == 0);
    fd.x = r0 ? pk2h(sw[WD2 + quad * 8 + 0], sw[WD2 + quad * 8 + 1]) : 0u;
    fd.y = r0 ? pk2h(sw[WD2 + quad * 8 + 2], sw[WD2 + quad * 8 + 3]) : 0u;
    fd.z = r0 ? pk2h(sw[WD2 + quad * 8 + 4], sw[WD2 + quad * 8 + 5]) : 0u;
    fd.w = r0 ? pk2h(sw[WD2 + quad * 8 + 6], sw[WD2 + quad * 8 + 7]) : 0u;
    half8 Waug0, Waug1, WdF;
    __builtin_memcpy(&Waug0, &fa, 16);
    __builtin_memcpy(&Waug1, &fb, 16);
    __builtin_memcpy(&WdF, &fd, 16);

#pragma unroll
    for (int g = 0; g < 4; ++g) {
      const uint32_t mm = s_mm[wv * 64 + g * 16 + m15];
      uint4 bm;
      bm.x = (quad == 0) ? mm : 0u;
      bm.y = (quad == 0) ? 0x00003C00u : 0u;   // halves (1.0, 0)
      bm.z = 0u; bm.w = 0u;
      half8 Bms; __builtin_memcpy(&Bms, &bm, 16);

      f32x4 ad0 = {0.f, 0.f, 0.f, 0.f}, ad1 = {0.f, 0.f, 0.f, 0.f};
      ad0 = __builtin_amdgcn_mfma_f32_16x16x32_f16(Waug0, Bms, ad0, 0, 0, 0);
      ad1 = __builtin_amdgcn_mfma_f32_16x16x32_f16(Waug1, Bms, ad1, 0, 0, 0);

      uint4 bh;
      bh.x = pk2h(fmaxf(ad0[0], 0.0f), fmaxf(ad0[1], 0.0f));
      bh.y = pk2h(fmaxf(ad0[2], 0.0f), fmaxf(ad0[3], 0.0f));
      bh.z = pk2h(fmaxf(ad1[0], 0.0f), fmaxf(ad1[1], 0.0f));
      bh.w = pk2h(fmaxf(ad1[2], 0.0f), fmaxf(ad1[3], 0.0f));
      if (g == 0) BhS0 = bh; else if (g == 1) BhS1 = bh;
      else if (g == 2) BhS2 = bh; else BhS3 = bh;

      half8 Bh; __builtin_memcpy(&Bh, &bh, 16);
      f32x4 as = {0.f, 0.f, 0.f, 0.f};
      as = __builtin_amdgcn_mfma_f32_16x16x32_f16(WdF, Bh, as, 0, 0, 0);
      if (quad == 0) s_sig[wv * 64 + g * 16 + m15] = as[0];  // sigma pre-bias
    }
  }
  const float sigf = softplus_f(s_sig[t] + bd2v);   // same-wave read

  // ---- fine phase, pass 2: color via MFMA (register-direct chain) ----
  {
    // Wc1 A-frags (fp16, hidden-permuted) — loaded here to shorten live ranges
    half8 Whi0, Whi1;
    if constexpr (USE_WS) {
      const uint4* frag = (const uint4*)((const char*)wsf + WS_FRAG_OFF);
      uint4 q0v = frag[lane * 2 + 0];
      uint4 q1v = frag[lane * 2 + 1];
      __builtin_memcpy(&Whi0, &q0v, 16);
      __builtin_memcpy(&Whi1, &q1v, 16);
    } else {
#pragma unroll
      for (int nt = 0; nt < 2; ++nt) {
        const int n_s = hperm(m15, nt);
        uint32_t hw[4];
#pragma unroll
        for (int j2 = 0; j2 < 4; ++j2) {
          const int k = quad * 8 + j2 * 2;
          hw[j2] = (uint32_t)f2h(Wc1[k * 32 + n_s])
                 | ((uint32_t)f2h(Wc1[(k + 1) * 32 + n_s]) << 16);
        }
        uint4 q = make_uint4(hw[0], hw[1], hw[2], hw[3]);
        if (nt == 0) __builtin_memcpy(&Whi0, &q, 16);
        else         __builtin_memcpy(&Whi1, &q, 16);
      }
    }
    const float4 dv0 = ldsf4(s_dv + quad * 8);       // hidden 8q..8q+3
    const float4 dv1 = ldsf4(s_dv + quad * 8 + 4);   // hidden 8q+4..8q+7
    uint4 qf = ((const uint4*)(sw + W24))[quad * 3 + (m15 < 3 ? m15 : 0)];
    if (m15 >= 3) qf = make_uint4(0u, 0u, 0u, 0u);
    half8 W2f; __builtin_memcpy(&W2f, &qf, 16);
    const float bc2x = sw[BC2 + 0], bc2y = sw[BC2 + 1], bc2z = sw[BC2 + 2];

#pragma unroll
    for (int g = 0; g < 4; ++g) {
      uint4 bh = (g == 0) ? BhS0 : (g == 1) ? BhS1 : (g == 2) ? BhS2 : BhS3;
      half8 Bh; __builtin_memcpy(&Bh, &bh, 16);

      f32x4 c0 = {0.f, 0.f, 0.f, 0.f}, c1 = {0.f, 0.f, 0.f, 0.f};
      c0 = __builtin_amdgcn_mfma_f32_16x16x32_f16(Whi0, Bh, c0, 0, 0, 0);
      c1 = __builtin_amdgcn_mfma_f32_16x16x32_f16(Whi1, Bh, c1, 0, 0, 0);

      uint4 bw;
      bw.x = pk2h(fmaxf(c0[0] + dv0.x, 0.0f), fmaxf(c0[1] + dv0.y, 0.0f));
      bw.y = pk2h(fmaxf(c0[2] + dv0.z, 0.0f), fmaxf(c0[3] + dv0.w, 0.0f));
      bw.z = pk2h(fmaxf(c1[0] + dv1.x, 0.0f), fmaxf(c1[1] + dv1.y, 0.0f));
      bw.w = pk2h(fmaxf(c1[2] + dv1.z, 0.0f), fmaxf(c1[3] + dv1.w, 0.0f));
      half8 Bav; __builtin_memcpy(&Bav, &bw, 16);

      f32x4 c2 = {0.f, 0.f, 0.f, 0.f};
      c2 = __builtin_amdgcn_mfma_f32_16x16x32_f16(W2f, Bav, c2, 0, 0, 0);
      if (quad == 0) {
        const int scol = wv * 64 + g * 16 + m15;
        float4 px;
        px.x = fast_rcp(1.0f + __expf(-(c2[0] + bc2x)));
        px.y = fast_rcp(1.0f + __expf(-(c2[1] + bc2y)));
        px.z = fast_rcp(1.0f + __expf(-(c2[2] + bc2z)));
        px.w = 0.0f;
        *(float4*)(s_rgb + scol * RGBS) = px;
      }
    }
  }

  // ---- fine alpha + parallel cumprod over 128 ----
  const float deltaf = (t < SF - 1) ? (s_zlf[t + 1] - zlf) : 0.0f;
  const float vf = __expf(-sigf * deltaf);
  const float af = 1.0f - vf;
  float fi = wave_scan_mul(vf, lane);
  if (lane == 63) s_tot[wv] = fi;
  __syncthreads();   // s_tot cross-wave (s_rgb reads below are same-wave)
  float efx = __shfl_up(fi, 1, 64); if (lane == 0) efx = 1.0f;
  const float wf = af * efx * (wv ? s_tot[0] : 1.0f);

  // ---- outputs ----
  float* o_img = out;
  float* o_w   = out + (size_t)n_rays * 3;
  float* o_z   = out + (size_t)n_rays * (3 + 128);
  float* o_inv = out + (size_t)n_rays * (3 + 256);

  o_w[(size_t)ray * 128 + t] = wf;
  o_z[(size_t)ray * 128 + t] = (zlf + 1.0f) * 0.5f;

  const float4 rgbv = ldsf4(s_rgb + t * RGBS);
  float r0 = wf * rgbv.x;
  float r1 = wf * rgbv.y;
  float r2 = wf * rgbv.z;
  float r3 = wf, r4 = wf * fast_rcp(zf);
#pragma unroll
  for (int d = 32; d > 0; d >>= 1) {
    r0 += __shfl_down(r0, d, 64);
    r1 += __shfl_down(r1, d, 64);
    r2 += __shfl_down(r2, d, 64);
    r3 += __shfl_down(r3, d, 64);
    r4 += __shfl_down(r4, d, 64);
  }
  if (lane == 0) {
    float* p = &s_red[wv * 5];
    p[0] = r0; p[1] = r1; p[2] = r2; p[3] = r3; p[4] = r4;
  }
  __syncthreads();
  if (t == 0) {
    const float accw = s_red[3] + s_red[8];
    const float bgw = 1.0f - accw;
    o_img[(size_t)ray * 3 + 0] = (s_red[0] + s_red[5]) + bgw * bg[0];
    o_img[(size_t)ray * 3 + 1] = (s_red[1] + s_red[6]) + bgw * bg[1];
    o_img[(size_t)ray * 3 + 2] = (s_red[2] + s_red[7]) + bgw * bg[2];
    o_inv[ray] = s_red[4] + s_red[9];
  }
}

extern "C" void kernel_launch(void* const* d_in, const int* in_sizes, int n_in,
                              void* d_out, int out_size, void* d_ws, size_t ws_size,
                              hipStream_t stream) {
  const float* h   = (const float*)d_in[1];
  const float* w   = (const float*)d_in[2];
  const float* K   = (const float*)d_in[3];
  const float* E   = (const float*)d_in[4];
  const float* bg  = (const float*)d_in[5];
  const float* Wd1 = (const float*)d_in[6];
  const float* bd1 = (const float*)d_in[7];
  const float* Wd2 = (const float*)d_in[8];
  const float* bd2 = (const float*)d_in[9];
  const float* Wc1 = (const float*)d_in[10];
  const float* bc1 = (const float*)d_in[11];
  const float* Wc2 = (const float*)d_in[12];
  const float* bc2 = (const float*)d_in[13];
  const int n_rays = in_sizes[1];
  float* wsf = (float*)d_ws;

  if (ws_size >= WS_NEED) {
    pack_weights<<<1, NT, 0, stream>>>(Wd1, bd1, Wd2, bd2, Wc1, bc1, Wc2, bc2, wsf);
    nerf_fwd<true><<<n_rays, NT, 0, stream>>>(h, w, K, E, bg, Wd1, bd1, Wd2, bd2,
                                              Wc1, bc1, Wc2, bc2, wsf,
                                              (float*)d_out, n_rays);
  } else {
    nerf_fwd<false><<<n_rays, NT, 0, stream>>>(h, w, K, E, bg, Wd1, bd1, Wd2, bd2,
                                               Wc1, bc1, Wc2, bc2, nullptr,
                                               (float*)d_out, n_rays);
  }
}

// Round 5
// 65.148 us; speedup vs baseline: 1.2363x; 1.0266x over previous
//
#include <hip/hip_runtime.h>
#include <stdint.h>

#define SC 192      // coarse samples (128 + 64)
#define SF 128      // fine (importance) samples
#define NT 128      // threads per block = 2 waves

// LDS weight-image offsets (floats)
#define WD1   0     // 96  (3x32 row-major) -- DEAD after staging; overlaid by s_dv[32] at runtime
#define BD1   96    // 32
#define WD2   128   // 32
#define BD2   160   // 1
#define BC2   161   // 3
#define NV4   164   // 32 x float4: (bc1[n], Wc1[32][n], Wc1[33][n], Wc1[34][n])
#define W24   292   // 12 x uint4: compact Wc2 fp16 A-frags, idx = quad*3 + channel
#define KIV   420   // 9 floats: precomputed inv(K) row-major (pack_weights)
#define SWTOT 432   // floats (108 float4s)

#define WS_FRAG_OFF 2048    // byte offset of Wc1 fp16 A-frags in d_ws
#define WS_NEED     4096

#define RGBS 4

using half8 = __attribute__((ext_vector_type(8))) _Float16;
using f32x4 = __attribute__((ext_vector_type(4))) float;
using f32x2 = __attribute__((ext_vector_type(2))) float;

__device__ __forceinline__ float zlog_c(int t) {
  return (t < 128) ? (-1.0f + (float)t * 0.0078125f)
                   : ((float)(t - 128) * 0.015625f);
}
__device__ __forceinline__ float delta_c(int t) {
  if (t >= SC - 1) return 0.0f;
  return zlog_c(t + 1) - zlog_c(t);
}

__device__ __forceinline__ float fast_rcp(float x) { return __builtin_amdgcn_rcpf(x); }
__device__ __forceinline__ float fast_rsq(float x) { return __builtin_amdgcn_rsqf(x); }
__device__ __forceinline__ float exp10_f(float x) { return __expf(x * 2.30258509299f); }
__device__ __forceinline__ float softplus_f(float x) {
  return fmaxf(x, 0.0f) + __logf(1.0f + __expf(-fabsf(x)));
}

// packed FP32 (CDNA VOP3P): 2 f32 ops per instruction — MI355X's 157 TF fp32
// spec rate is exactly the packed rate (scalar v_fma_f32 is half, m07).
__device__ __forceinline__ f32x2 pk_fma2(f32x2 a, f32x2 b, f32x2 c) {
  f32x2 d;
  asm("v_pk_fma_f32 %0, %1, %2, %3" : "=v"(d) : "v"(a), "v"(b), "v"(c));
  return d;
}
__device__ __forceinline__ f32x2 pk_add2(f32x2 a, f32x2 b) {
  f32x2 d;
  asm("v_pk_add_f32 %0, %1, %2" : "=v"(d) : "v"(a), "v"(b));
  return d;
}

// fp16 helpers: pk2h = 1 HW instr (v_cvt_pkrtz_f16_f32); f2h = RTN scalar convert
__device__ __forceinline__ uint32_t pk2h(float a, float b) {
  auto p = __builtin_amdgcn_cvt_pkrtz(a, b);
  uint32_t u; __builtin_memcpy(&u, &p, 4); return u;
}
__device__ __forceinline__ unsigned short f2h(float f) {
  _Float16 h = (_Float16)f;
  unsigned short us; __builtin_memcpy(&us, &h, 2); return us;
}

__device__ __forceinline__ float4 ldsf4(const float* p) { return *(const float4*)p; }

// hidden-axis permutation for MFMA A-frags: frag0 row i -> hidden 8*(i>>2)+(i&3),
// frag1 row i -> +4. Then C rows (row = quad*4+reg) map to hidden 8*quad+reg(+4),
// so relu-packed C output lands register-direct as the NEXT MFMA's B-frag
// (k = quad*8 + j = true hidden index). No LDS round-trips.
__device__ __forceinline__ int hperm(int i, int ntf) {
  return 8 * (i >> 2) + (i & 3) + ntf * 4;
}

// JAX threefry2x32 with key = (0, 42)
__device__ __forceinline__ void threefry2x32_k42(uint32_t& x0, uint32_t& x1) {
  const uint32_t ks0 = 0u, ks1 = 42u;
  const uint32_t ks2 = ks0 ^ ks1 ^ 0x1BD11BDAu;
  const uint32_t ks[3] = {ks0, ks1, ks2};
  const int rot[2][4] = {{13, 15, 26, 6}, {17, 29, 16, 24}};
  x0 += ks[0];
  x1 += ks[1];
#pragma unroll
  for (int i = 0; i < 5; ++i) {
#pragma unroll
    for (int j = 0; j < 4; ++j) {
      x0 += x1;
      const int r = rot[i & 1][j];
      x1 = (x1 << r) | (x1 >> (32 - r));
      x1 ^= x0;
    }
    x0 += ks[(i + 1) % 3];
    x1 += ks[(i + 2) % 3] + (uint32_t)(i + 1);
  }
}

__device__ __forceinline__ float wave_scan_mul(float v, int lane) {
#pragma unroll
  for (int d = 1; d < 64; d <<= 1) {
    float o = __shfl_up(v, d, 64);
    if (lane >= d) v *= o;
  }
  return v;
}
__device__ __forceinline__ float wave_scan_add(float v, int lane) {
#pragma unroll
  for (int d = 1; d < 64; d <<= 1) {
    float o = __shfl_up(v, d, 64);
    if (lane >= d) v += o;
  }
  return v;
}

// ---- pre-pack kernel: weight image + K-inverse + fp16 Wc1 A-frags ----
__global__ __launch_bounds__(NT) void pack_weights(
    const float* __restrict__ K,
    const float* __restrict__ Wd1, const float* __restrict__ bd1,
    const float* __restrict__ Wd2, const float* __restrict__ bd2,
    const float* __restrict__ Wc1, const float* __restrict__ bc1,
    const float* __restrict__ Wc2, const float* __restrict__ bc2,
    float* __restrict__ wsf) {
  const int t = threadIdx.x;
  for (int i = t; i < 96; i += NT) wsf[WD1 + i] = Wd1[i];
  for (int i = t; i < 32; i += NT) { wsf[BD1 + i] = bd1[i]; wsf[WD2 + i] = Wd2[i]; }
  if (t == 0) {
    wsf[BD2] = bd2[0];
    wsf[BC2 + 0] = bc2[0]; wsf[BC2 + 1] = bc2[1]; wsf[BC2 + 2] = bc2[2];
    // K-inverse (identical float expressions to the former in-kernel version)
    const float k00 = K[0], k01 = K[1], k02 = K[2];
    const float k10 = K[3], k11 = K[4], k12 = K[5];
    const float k20 = K[6], k21 = K[7], k22 = K[8];
    const float det = k00 * (k11 * k22 - k12 * k21)
                    - k01 * (k10 * k22 - k12 * k20)
                    + k02 * (k10 * k21 - k11 * k20);
    const float id = 1.0f / det;
    wsf[KIV + 0] =  (k11 * k22 - k12 * k21) * id;
    wsf[KIV + 1] = -(k01 * k22 - k02 * k21) * id;
    wsf[KIV + 2] =  (k01 * k12 - k02 * k11) * id;
    wsf[KIV + 3] = -(k10 * k22 - k12 * k20) * id;
    wsf[KIV + 4] =  (k00 * k22 - k02 * k20) * id;
    wsf[KIV + 5] = -(k00 * k12 - k02 * k10) * id;
    wsf[KIV + 6] =  (k10 * k21 - k11 * k20) * id;
    wsf[KIV + 7] = -(k00 * k21 - k01 * k20) * id;
    wsf[KIV + 8] =  (k00 * k11 - k01 * k10) * id;
  }
  if (t < 32) {
    wsf[NV4 + t * 4 + 0] = bc1[t];
    wsf[NV4 + t * 4 + 1] = Wc1[32 * 32 + t];
    wsf[NV4 + t * 4 + 2] = Wc1[33 * 32 + t];
    wsf[NV4 + t * 4 + 3] = Wc1[34 * 32 + t];
  }
  // compact Wc2 fp16 A-frags for MFMA2 (16x16x32): A[m=channel][k=n]
  if (t < 12) {
    const int m = t % 3, q = t / 3;
    uint32_t hw[4];
#pragma unroll
    for (int j2 = 0; j2 < 4; ++j2) {
      const int k0 = q * 8 + j2 * 2;
      hw[j2] = (uint32_t)f2h(Wc2[k0 * 3 + m])
             | ((uint32_t)f2h(Wc2[(k0 + 1) * 3 + m]) << 16);
    }
    ((uint4*)(wsf + W24))[t] = make_uint4(hw[0], hw[1], hw[2], hw[3]);
  }
  // Wc1[0:32][:] fp16 A-frags (hidden-permuted): frag[lane*2 + nt]
  if (t < 64) {
    const int q_s = t >> 4;
    const int i = t & 15;
    uint4* frag = (uint4*)((char*)wsf + WS_FRAG_OFF);
#pragma unroll
    for (int nt = 0; nt < 2; ++nt) {
      const int n_s = hperm(i, nt);
      uint32_t hw[4];
#pragma unroll
      for (int j2 = 0; j2 < 4; ++j2) {
        const int k = q_s * 8 + j2 * 2;
        hw[j2] = (uint32_t)f2h(Wc1[k * 32 + n_s])
               | ((uint32_t)f2h(Wc1[(k + 1) * 32 + n_s]) << 16);
      }
      frag[t * 2 + nt] = make_uint4(hw[0], hw[1], hw[2], hw[3]);
    }
  }
}

template <bool USE_WS>
__global__ __launch_bounds__(NT, 8) void nerf_fwd(
    const float* __restrict__ hh, const float* __restrict__ ww,
    const float* __restrict__ K, const float* __restrict__ E,
    const float* __restrict__ bg,
    const float* __restrict__ Wd1, const float* __restrict__ bd1,
    const float* __restrict__ Wd2, const float* __restrict__ bd2,
    const float* __restrict__ Wc1, const float* __restrict__ bc1,
    const float* __restrict__ Wc2, const float* __restrict__ bc2,
    const float* __restrict__ wsf,
    float* __restrict__ out, int n_rays) {
  const int ray = blockIdx.x;
  const int t = threadIdx.x;
  const int lane = t & 63;
  const int wv = t >> 6;   // 0 or 1
  const int quad = lane >> 4;
  const int m15 = lane & 15;

  __shared__ __align__(16) float sw[SWTOT];
  __shared__ __align__(16) float s_A[32];
  __shared__ __align__(16) float s_B[32];
  // phase-union: coarse {s_w[192], s_cdf[192]} then fine {s_mm[128], s_sig[128], s_rgb[512]}
  __shared__ __align__(16) unsigned char u_buf[3072];
  float*    const s_w   = (float*)u_buf;                 // coarse
  float*    const s_cdf = (float*)(u_buf + 768);         // coarse
  uint32_t* const s_mm  = (uint32_t*)u_buf;              // fine: packed (ms,msz) fp16
  float*    const s_sig = (float*)(u_buf + 512);         // fine: sigma pre-softplus/bias
  float*    const s_rgb = (float*)(u_buf + 1024);        // fine: raw rgb logits (RGBS stride)
  __shared__ float s_zlf[SF];
  __shared__ float s_tot[8];
  __shared__ float s_red[16];
  float* const s_dv = sw;   // overlay on dead WD1 region (never read after staging)

  // ---- stage weight image into LDS ----
  if constexpr (USE_WS) {
    const float4* wsrc = (const float4*)wsf;
    float4* sdst = (float4*)sw;
    for (int i = t; i < SWTOT / 4; i += NT) sdst[i] = wsrc[i];
  } else {
    for (int i = t; i < 96; i += NT) sw[WD1 + i] = Wd1[i];
    for (int i = t; i < 32; i += NT) { sw[BD1 + i] = bd1[i]; sw[WD2 + i] = Wd2[i]; }
    if (t == 0) {
      sw[BD2] = bd2[0];
      sw[BC2 + 0] = bc2[0]; sw[BC2 + 1] = bc2[1]; sw[BC2 + 2] = bc2[2];
    }
    if (t < 32) {
      sw[NV4 + t * 4 + 0] = bc1[t];
      sw[NV4 + t * 4 + 1] = Wc1[32 * 32 + t];
      sw[NV4 + t * 4 + 2] = Wc1[33 * 32 + t];
      sw[NV4 + t * 4 + 3] = Wc1[34 * 32 + t];
    }
    if (t < 12) {
      const int m = t % 3, q = t / 3;
      uint32_t hw[4];
#pragma unroll
      for (int j2 = 0; j2 < 4; ++j2) {
        const int k0 = q * 8 + j2 * 2;
        hw[j2] = (uint32_t)f2h(Wc2[k0 * 3 + m])
               | ((uint32_t)f2h(Wc2[(k0 + 1) * 3 + m]) << 16);
      }
      ((uint4*)(sw + W24))[t] = make_uint4(hw[0], hw[1], hw[2], hw[3]);
    }
  }

  // ---- ray setup ----
  float i00, i01, i02, i10, i11, i12, i20, i21, i22;
  if constexpr (USE_WS) {
    // uniform address -> scalar loads, zero VALU
    i00 = wsf[KIV + 0]; i01 = wsf[KIV + 1]; i02 = wsf[KIV + 2];
    i10 = wsf[KIV + 3]; i11 = wsf[KIV + 4]; i12 = wsf[KIV + 5];
    i20 = wsf[KIV + 6]; i21 = wsf[KIV + 7]; i22 = wsf[KIV + 8];
  } else {
    const float k00 = K[0], k01 = K[1], k02 = K[2];
    const float k10 = K[3], k11 = K[4], k12 = K[5];
    const float k20 = K[6], k21 = K[7], k22 = K[8];
    const float det = k00 * (k11 * k22 - k12 * k21)
                    - k01 * (k10 * k22 - k12 * k20)
                    + k02 * (k10 * k21 - k11 * k20);
    const float id = 1.0f / det;
    i00 =  (k11 * k22 - k12 * k21) * id;
    i01 = -(k01 * k22 - k02 * k21) * id;
    i02 =  (k01 * k12 - k02 * k11) * id;
    i10 = -(k10 * k22 - k12 * k20) * id;
    i11 =  (k00 * k22 - k02 * k20) * id;
    i12 = -(k00 * k12 - k02 * k10) * id;
    i20 =  (k10 * k21 - k11 * k20) * id;
    i21 = -(k00 * k21 - k01 * k20) * id;
    i22 =  (k00 * k11 - k01 * k10) * id;
  }

  const float dwx = ww[ray] + 0.5f;
  const float dwy = hh[ray] + 0.5f;
  const float cx = i00 * dwx + i01 * dwy + i02;
  const float cy = i10 * dwx + i11 * dwy + i12;
  const float cz = i20 * dwx + i21 * dwy + i22;
  const float* Er = E + (size_t)ray * 16;
  const float ox = Er[3], oy = Er[7], oz = Er[11];
  const float dx = Er[0] * cx + Er[1] * cy + Er[2] * cz;
  const float dy = Er[4] * cx + Er[5] * cy + Er[6] * cz;
  const float dz = Er[8] * cx + Er[9] * cy + Er[10] * cz;
  const float dd = dx * dx + dy * dy + dz * dz;
  const float inv_nrm = fast_rsq(dd);
  const float ndx = dx * inv_nrm, ndy = dy * inv_nrm, ndz = dz * inv_nrm;
  // quadratic-expansion constants for dist^2 = |o + d z|^2
  const float oo  = ox * ox + oy * oy + oz * oz;
  const float od2 = 2.0f * (ox * dx + oy * dy + oz * dz);

  // A_n = o . Wd1[:,n], B_n = d . Wd1[:,n]  (per-ray, 32 threads, reads global Wd1)
  if (t < 32) {
    const float w0 = Wd1[t], w1 = Wd1[32 + t], w2 = Wd1[64 + t];
    s_A[t] = ox * w0 + oy * w1 + oz * w2;
    s_B[t] = dx * w0 + dy * w1 + dz * w2;
  }

  __syncthreads();   // weights + A/B staged

  // per-ray dv table: dv_n = bc1[n] + nd . Wc1[32:35][:,n]  (overlays dead WD1 region)
  if (t < 32) {
    const float4 nv = ldsf4(sw + NV4 + t * 4);
    s_dv[t] = nv.x + ndx * nv.y + ndy * nv.z + ndz * nv.w;
  }

  // ---- coarse pass (f32, packed): e0 = t (all); e1 = 128+t (wave 0, fused) ----
  // h_n = relu(ms*A_n + msz*B_n + b_n); sigma = wd.h  — pk_fma pairs, 2 units/instr
  const float bd2v = sw[BD2];
  float a0, v0, a1e = 0.0f, v1e = 1.0f;
  {
    float ms0, msz0, ms1 = 0.f, msz1 = 0.f;
    {
      const float z = exp10_f(zlog_c(t));
      const float d2 = fmaf(z, fmaf(z, dd, od2), oo);
      const float r = fast_rsq(fmaxf(d2, 1.0f));
      ms0 = (2.0f - r) * r;
      msz0 = ms0 * z;
    }
    if (wv == 0) {
      const float z = exp10_f((float)t * 0.015625f);   // zlog_c(128+t)
      const float d2 = fmaf(z, fmaf(z, dd, od2), oo);
      const float r = fast_rsq(fmaxf(d2, 1.0f));
      ms1 = (2.0f - r) * r;
      msz1 = ms1 * z;
    }
    const f32x2 msp0 = {ms0, ms0}, mszp0 = {msz0, msz0};
    const f32x2 msp1 = {ms1, ms1}, mszp1 = {msz1, msz1};
    f32x2 ac0a = {0.f, 0.f}, ac0b = {0.f, 0.f};
    f32x2 ac1a = {0.f, 0.f}, ac1b = {0.f, 0.f};
    if (wv == 0) {  // wave-uniform branch: fused 2-sample loop (coeffs loaded once)
#pragma unroll 2
      for (int c = 0; c < 8; ++c) {
        const int k4 = c * 4;
        const float4 A  = ldsf4(s_A + k4);
        const float4 B  = ldsf4(s_B + k4);
        const float4 b  = ldsf4(sw + BD1 + k4);
        const float4 wd = ldsf4(sw + WD2 + k4);
        const f32x2 Axy = {A.x, A.y}, Azw = {A.z, A.w};
        const f32x2 Bxy = {B.x, B.y}, Bzw = {B.z, B.w};
        const f32x2 bxy = {b.x, b.y}, bzw = {b.z, b.w};
        const f32x2 wxy = {wd.x, wd.y}, wzw = {wd.z, wd.w};
        f32x2 p;
        p = pk_fma2(mszp0, Bxy, pk_fma2(msp0, Axy, bxy));
        p.x = fmaxf(p.x, 0.f); p.y = fmaxf(p.y, 0.f);
        ac0a = pk_fma2(p, wxy, ac0a);
        p = pk_fma2(mszp0, Bzw, pk_fma2(msp0, Azw, bzw));
        p.x = fmaxf(p.x, 0.f); p.y = fmaxf(p.y, 0.f);
        ac0b = pk_fma2(p, wzw, ac0b);
        p = pk_fma2(mszp1, Bxy, pk_fma2(msp1, Axy, bxy));
        p.x = fmaxf(p.x, 0.f); p.y = fmaxf(p.y, 0.f);
        ac1a = pk_fma2(p, wxy, ac1a);
        p = pk_fma2(mszp1, Bzw, pk_fma2(msp1, Azw, bzw));
        p.x = fmaxf(p.x, 0.f); p.y = fmaxf(p.y, 0.f);
        ac1b = pk_fma2(p, wzw, ac1b);
      }
    } else {
#pragma unroll 2
      for (int c = 0; c < 8; ++c) {
        const int k4 = c * 4;
        const float4 A  = ldsf4(s_A + k4);
        const float4 B  = ldsf4(s_B + k4);
        const float4 b  = ldsf4(sw + BD1 + k4);
        const float4 wd = ldsf4(sw + WD2 + k4);
        const f32x2 Axy = {A.x, A.y}, Azw = {A.z, A.w};
        const f32x2 Bxy = {B.x, B.y}, Bzw = {B.z, B.w};
        const f32x2 bxy = {b.x, b.y}, bzw = {b.z, b.w};
        const f32x2 wxy = {wd.x, wd.y}, wzw = {wd.z, wd.w};
        f32x2 p;
        p = pk_fma2(mszp0, Bxy, pk_fma2(msp0, Axy, bxy));
        p.x = fmaxf(p.x, 0.f); p.y = fmaxf(p.y, 0.f);
        ac0a = pk_fma2(p, wxy, ac0a);
        p = pk_fma2(mszp0, Bzw, pk_fma2(msp0, Azw, bzw));
        p.x = fmaxf(p.x, 0.f); p.y = fmaxf(p.y, 0.f);
        ac0b = pk_fma2(p, wzw, ac0b);
      }
    }
    const float acc0 = bd2v + ((ac0a.x + ac0a.y) + (ac0b.x + ac0b.y));
    v0 = __expf(-softplus_f(acc0) * delta_c(t));
    a0 = 1.0f - v0;
    if (wv == 0) {
      const float acc1 = bd2v + ((ac1a.x + ac1a.y) + (ac1b.x + ac1b.y));
      v1e = __expf(-softplus_f(acc1) * delta_c(128 + t));
      a1e = 1.0f - v1e;
    }
  }

  // parallel cumprod of (1-alpha)
  float i0 = wave_scan_mul(v0, lane);
  float i1 = 1.0f;
  if (wv == 0) i1 = wave_scan_mul(v1e, lane);
  if (lane == 63) s_tot[wv] = i0;
  if (wv == 0 && lane == 63) s_tot[2] = i1;
  __syncthreads();
  {
    const float preC1 = s_tot[0];
    const float preC2 = s_tot[0] * s_tot[1];
    float e0x = __shfl_up(i0, 1, 64); if (lane == 0) e0x = 1.0f;
    s_w[t] = a0 * e0x * (wv ? preC1 : 1.0f);
    if (wv == 0) {
      float e1x = __shfl_up(i1, 1, 64); if (lane == 0) e1x = 1.0f;
      s_w[128 + t] = a1e * e1x * preC2;
    }
  }
  __syncthreads();

  // reweight
  float wre0, wre1 = 0.0f;
  {
    const float wm = (t > 0) ? s_w[t - 1] : 0.0f;
    const float w0 = s_w[t];
    const float wp = s_w[t + 1];
    wre0 = 0.5f * (fmaxf(wm, w0) + fmaxf(w0, wp)) + (0.02f / 192.0f);
    wre0 *= (t < 128) ? (128.0f / 192.0f) : (64.0f / 192.0f);
  }
  if (wv == 0) {
    const int e = 128 + t;
    const float wm = s_w[e - 1];
    const float w0 = s_w[e];
    const float wp = (e < SC - 1) ? s_w[e + 1] : 0.0f;
    wre1 = 0.5f * (fmaxf(wm, w0) + fmaxf(w0, wp)) + (0.02f / 192.0f);
    wre1 *= (64.0f / 192.0f);
  }

  // parallel cumsum -> normalized CDF
  float s0 = wave_scan_add(wre0, lane);
  float s1 = 0.0f;
  if (wv == 0) s1 = wave_scan_add(wre1, lane);
  if (lane == 63) s_tot[4 + wv] = s0;
  if (wv == 0 && lane == 63) s_tot[6] = s1;
  __syncthreads();
  {
    const float T0 = s_tot[4], T1 = s_tot[5], T2 = s_tot[6];
    const float inv_total = fast_rcp(T0 + T1 + T2);
    s_cdf[t] = (s0 + (wv ? T0 : 0.0f)) * inv_total;
    if (wv == 0) s_cdf[128 + t] = (s1 + T0 + T1) * inv_total;
  }
  __syncthreads();

  // ---- importance sampling ----
  float zlf, zf;
  {
    const uint32_t total = (uint32_t)n_rays * 128u;
    const uint32_t halfc = total >> 1;
    const uint32_t j = (uint32_t)ray * 128u + (uint32_t)t;
    uint32_t x0, x1;
    const bool first = (j < halfc);
    if (first) { x0 = j; x1 = j + halfc; } else { x0 = j - halfc; x1 = j; }
    threefry2x32_k42(x0, x1);
    const uint32_t bits = first ? x0 : x1;
    const float fr = __uint_as_float((bits >> 9) | 0x3f800000u) - 1.0f;

    float u = (float)t * 0.0078125f + fr * 0.0078125f;
    u = u * (s_cdf[190] - s_cdf[1]) + s_cdf[1];

    int lo = 0, hi = 189;
    while (lo < hi) {
      const int mid = (lo + hi) >> 1;
      if (s_cdf[1 + mid] <= u) lo = mid + 1; else hi = mid;
    }
    const int inds = lo + 1;
    const float cb = s_cdf[inds - 1], ca = s_cdf[inds];
    const float tt = (u - cb) * fast_rcp(ca - cb);
    const float zb = 0.5f * (zlog_c(inds - 1) + zlog_c(inds));
    const float za = 0.5f * (zlog_c(inds) + zlog_c(inds + 1));
    zlf = zb + (za - zb) * tt;
    s_zlf[t] = zlf;
    zf = exp10_f(zlf);
  }
  __syncthreads();   // last s_cdf read — union area now free for s_mm/s_sig/s_rgb

  // ---- fine phase, pass 1: density via MFMA ----
  // input per sample = (ms, msz, 1); h = relu([A;B;b] @ (ms,msz,1)); sigma = wd.h
  // All LDS traffic below is same-wave (wave wv touches only samples wv*64..+63).
  {
    const float d2 = fmaf(zf, fmaf(zf, dd, od2), oo);
    const float r = fast_rsq(fmaxf(d2, 1.0f));
    const float msf = (2.0f - r) * r;
    s_mm[t] = pk2h(msf, msf * zf);
  }

  uint4 BhS0, BhS1, BhS2, BhS3;   // per-group packed h (fp16 B-frags), pass1 -> pass2
  {
    const bool q0 = (quad == 0);
    const int ma = hperm(m15, 0), mb = hperm(m15, 1);
    uint4 fa, fb, fd;
    fa.x = q0 ? pk2h(s_A[ma], s_B[ma]) : 0u;
    fa.y = q0 ? (uint32_t)f2h(sw[BD1 + ma]) : 0u;
    fa.z = 0u; fa.w = 0u;
    fb.x = q0 ? pk2h(s_A[mb], s_B[mb]) : 0u;
    fb.y = q0 ? (uint32_t)f2h(sw[BD1 + mb]) : 0u;
    fb.z = 0u; fb.w = 0u;
    const bool r0 = (m15 == 0);
    fd.x = r0 ? pk2h(sw[WD2 + quad * 8 + 0], sw[WD2 + quad * 8 + 1]) : 0u;
    fd.y = r0 ? pk2h(sw[WD2 + quad * 8 + 2], sw[WD2 + quad * 8 + 3]) : 0u;
    fd.z = r0 ? pk2h(sw[WD2 + quad * 8 + 4], sw[WD2 + quad * 8 + 5]) : 0u;
    fd.w = r0 ? pk2h(sw[WD2 + quad * 8 + 6], sw[WD2 + quad * 8 + 7]) : 0u;
    half8 Waug0, Waug1, WdF;
    __builtin_memcpy(&Waug0, &fa, 16);
    __builtin_memcpy(&Waug1, &fb, 16);
    __builtin_memcpy(&WdF, &fd, 16);

#pragma unroll
    for (int g = 0; g < 4; ++g) {
      const uint32_t mm = s_mm[wv * 64 + g * 16 + m15];
      uint4 bm;
      bm.x = (quad == 0) ? mm : 0u;
      bm.y = (quad == 0) ? 0x00003C00u : 0u;   // halves (1.0, 0)
      bm.z = 0u; bm.w = 0u;
      half8 Bms; __builtin_memcpy(&Bms, &bm, 16);

      f32x4 ad0 = {0.f, 0.f, 0.f, 0.f}, ad1 = {0.f, 0.f, 0.f, 0.f};
      ad0 = __builtin_amdgcn_mfma_f32_16x16x32_f16(Waug0, Bms, ad0, 0, 0, 0);
      ad1 = __builtin_amdgcn_mfma_f32_16x16x32_f16(Waug1, Bms, ad1, 0, 0, 0);

      uint4 bh;
      bh.x = pk2h(fmaxf(ad0[0], 0.0f), fmaxf(ad0[1], 0.0f));
      bh.y = pk2h(fmaxf(ad0[2], 0.0f), fmaxf(ad0[3], 0.0f));
      bh.z = pk2h(fmaxf(ad1[0], 0.0f), fmaxf(ad1[1], 0.0f));
      bh.w = pk2h(fmaxf(ad1[2], 0.0f), fmaxf(ad1[3], 0.0f));
      if (g == 0) BhS0 = bh; else if (g == 1) BhS1 = bh;
      else if (g == 2) BhS2 = bh; else BhS3 = bh;

      half8 Bh; __builtin_memcpy(&Bh, &bh, 16);
      f32x4 as = {0.f, 0.f, 0.f, 0.f};
      as = __builtin_amdgcn_mfma_f32_16x16x32_f16(WdF, Bh, as, 0, 0, 0);
      if (quad == 0) s_sig[wv * 64 + g * 16 + m15] = as[0];  // sigma pre-bias
    }
  }
  const float sigf = softplus_f(s_sig[t] + bd2v);   // same-wave read

  // ---- fine phase, pass 2: color via MFMA (register-direct chain) ----
  // Stores RAW rgb logits (pre-bias, pre-sigmoid); sigmoid applied at output
  // stage where all 64 lanes do exactly 3 (vs 12 under quad0 exec-mask here).
  {
    half8 Whi0, Whi1;
    if constexpr (USE_WS) {
      const uint4* frag = (const uint4*)((const char*)wsf + WS_FRAG_OFF);
      uint4 q0v = frag[lane * 2 + 0];
      uint4 q1v = frag[lane * 2 + 1];
      __builtin_memcpy(&Whi0, &q0v, 16);
      __builtin_memcpy(&Whi1, &q1v, 16);
    } else {
#pragma unroll
      for (int nt = 0; nt < 2; ++nt) {
        const int n_s = hperm(m15, nt);
        uint32_t hw[4];
#pragma unroll
        for (int j2 = 0; j2 < 4; ++j2) {
          const int k = quad * 8 + j2 * 2;
          hw[j2] = (uint32_t)f2h(Wc1[k * 32 + n_s])
                 | ((uint32_t)f2h(Wc1[(k + 1) * 32 + n_s]) << 16);
        }
        uint4 q = make_uint4(hw[0], hw[1], hw[2], hw[3]);
        if (nt == 0) __builtin_memcpy(&Whi0, &q, 16);
        else         __builtin_memcpy(&Whi1, &q, 16);
      }
    }
    const float4 dv0 = ldsf4(s_dv + quad * 8);       // hidden 8q..8q+3
    const float4 dv1 = ldsf4(s_dv + quad * 8 + 4);   // hidden 8q+4..8q+7
    uint4 qf = ((const uint4*)(sw + W24))[quad * 3 + (m15 < 3 ? m15 : 0)];
    if (m15 >= 3) qf = make_uint4(0u, 0u, 0u, 0u);
    half8 W2f; __builtin_memcpy(&W2f, &qf, 16);

#pragma unroll
    for (int g = 0; g < 4; ++g) {
      uint4 bh = (g == 0) ? BhS0 : (g == 1) ? BhS1 : (g == 2) ? BhS2 : BhS3;
      half8 Bh; __builtin_memcpy(&Bh, &bh, 16);

      f32x4 c0 = {0.f, 0.f, 0.f, 0.f}, c1 = {0.f, 0.f, 0.f, 0.f};
      c0 = __builtin_amdgcn_mfma_f32_16x16x32_f16(Whi0, Bh, c0, 0, 0, 0);
      c1 = __builtin_amdgcn_mfma_f32_16x16x32_f16(Whi1, Bh, c1, 0, 0, 0);

      uint4 bw;
      bw.x = pk2h(fmaxf(c0[0] + dv0.x, 0.0f), fmaxf(c0[1] + dv0.y, 0.0f));
      bw.y = pk2h(fmaxf(c0[2] + dv0.z, 0.0f), fmaxf(c0[3] + dv0.w, 0.0f));
      bw.z = pk2h(fmaxf(c1[0] + dv1.x, 0.0f), fmaxf(c1[1] + dv1.y, 0.0f));
      bw.w = pk2h(fmaxf(c1[2] + dv1.z, 0.0f), fmaxf(c1[3] + dv1.w, 0.0f));
      half8 Bav; __builtin_memcpy(&Bav, &bw, 16);

      f32x4 c2 = {0.f, 0.f, 0.f, 0.f};
      c2 = __builtin_amdgcn_mfma_f32_16x16x32_f16(W2f, Bav, c2, 0, 0, 0);
      if (quad == 0) {
        const int scol = wv * 64 + g * 16 + m15;
        *(f32x4*)(s_rgb + scol * RGBS) = c2;   // raw logits; c2[3] == 0
      }
    }
  }

  // ---- fine alpha + parallel cumprod over 128 ----
  const float deltaf = (t < SF - 1) ? (s_zlf[t + 1] - zlf) : 0.0f;
  const float vf = __expf(-sigf * deltaf);
  const float af = 1.0f - vf;
  float fi = wave_scan_mul(vf, lane);
  if (lane == 63) s_tot[wv] = fi;
  __syncthreads();   // s_tot cross-wave (s_rgb reads below are same-wave)
  float efx = __shfl_up(fi, 1, 64); if (lane == 0) efx = 1.0f;
  const float wf = af * efx * (wv ? s_tot[0] : 1.0f);

  // ---- outputs ----
  float* o_img = out;
  float* o_w   = out + (size_t)n_rays * 3;
  float* o_z   = out + (size_t)n_rays * (3 + 128);
  float* o_inv = out + (size_t)n_rays * (3 + 256);

  o_w[(size_t)ray * 128 + t] = wf;
  o_z[(size_t)ray * 128 + t] = (zlf + 1.0f) * 0.5f;

  const float bc2x = sw[BC2 + 0], bc2y = sw[BC2 + 1], bc2z = sw[BC2 + 2];
  const float4 rgbv = ldsf4(s_rgb + t * RGBS);
  const float sr = fast_rcp(1.0f + __expf(-(rgbv.x + bc2x)));
  const float sg = fast_rcp(1.0f + __expf(-(rgbv.y + bc2y)));
  const float sb = fast_rcp(1.0f + __expf(-(rgbv.z + bc2z)));

  f32x2 p01 = {wf * sr, wf * sg};
  f32x2 p23 = {wf * sb, wf};
  float r4 = wf * fast_rcp(zf);
#pragma unroll
  for (int d = 32; d > 0; d >>= 1) {
    f32x2 o01, o23;
    o01.x = __shfl_down(p01.x, d, 64);
    o01.y = __shfl_down(p01.y, d, 64);
    o23.x = __shfl_down(p23.x, d, 64);
    o23.y = __shfl_down(p23.y, d, 64);
    p01 = pk_add2(p01, o01);
    p23 = pk_add2(p23, o23);
    r4 += __shfl_down(r4, d, 64);
  }
  if (lane == 0) {
    float* p = &s_red[wv * 5];
    p[0] = p01.x; p[1] = p01.y; p[2] = p23.x; p[3] = p23.y; p[4] = r4;
  }
  __syncthreads();
  if (t == 0) {
    const float accw = s_red[3] + s_red[8];
    const float bgw = 1.0f - accw;
    o_img[(size_t)ray * 3 + 0] = (s_red[0] + s_red[5]) + bgw * bg[0];
    o_img[(size_t)ray * 3 + 1] = (s_red[1] + s_red[6]) + bgw * bg[1];
    o_img[(size_t)ray * 3 + 2] = (s_red[2] + s_red[7]) + bgw * bg[2];
    o_inv[ray] = s_red[4] + s_red[9];
  }
}

extern "C" void kernel_launch(void* const* d_in, const int* in_sizes, int n_in,
                              void* d_out, int out_size, void* d_ws, size_t ws_size,
                              hipStream_t stream) {
  const float* h   = (const float*)d_in[1];
  const float* w   = (const float*)d_in[2];
  const float* K   = (const float*)d_in[3];
  const float* E   = (const float*)d_in[4];
  const float* bg  = (const float*)d_in[5];
  const float* Wd1 = (const float*)d_in[6];
  const float* bd1 = (const float*)d_in[7];
  const float* Wd2 = (const float*)d_in[8];
  const float* bd2 = (const float*)d_in[9];
  const float* Wc1 = (const float*)d_in[10];
  const float* bc1 = (const float*)d_in[11];
  const float* Wc2 = (const float*)d_in[12];
  const float* bc2 = (const float*)d_in[13];
  const int n_rays = in_sizes[1];
  float* wsf = (float*)d_ws;

  if (ws_size >= WS_NEED) {
    pack_weights<<<1, NT, 0, stream>>>(K, Wd1, bd1, Wd2, bd2, Wc1, bc1, Wc2, bc2, wsf);
    nerf_fwd<true><<<n_rays, NT, 0, stream>>>(h, w, K, E, bg, Wd1, bd1, Wd2, bd2,
                                              Wc1, bc1, Wc2, bc2, wsf,
                                              (float*)d_out, n_rays);
  } else {
    nerf_fwd<false><<<n_rays, NT, 0, stream>>>(h, w, K, E, bg, Wd1, bd1, Wd2, bd2,
                                               Wc1, bc1, Wc2, bc2, nullptr,
                                               (float*)d_out, n_rays);
  }
}

// Round 9
// 63.947 us; speedup vs baseline: 1.2595x; 1.0188x over previous
//
#include <hip/hip_runtime.h>
#include <stdint.h>

#define SC 192      // coarse samples (128 + 64)
#define SF 128      // fine (importance) samples
#define NT 128      // threads per block = 2 waves

// LDS weight-image offsets (floats)
#define WD1   0     // 96  (3x32 row-major) -- DEAD after staging; overlaid by s_dv[32] at runtime
#define BD1   96    // 32
#define WD2   128   // 32
#define BD2   160   // 1
#define BC2   161   // 3
#define NV4   164   // 32 x float4: (bc1[n], Wc1[32][n], Wc1[33][n], Wc1[34][n])
#define W24   292   // 12 x uint4: compact Wc2 fp16 A-frags, idx = quad*3 + channel
#define KIV   420   // 9 floats: precomputed inv(K) row-major (pack_weights)
#define SWTOT 432   // floats (108 float4s)

#define WS_FRAG_OFF 2048    // byte offset of Wc1 fp16 A-frags in d_ws
#define WS_NEED     4096

#define RGBS 4

using half8 = __attribute__((ext_vector_type(8))) _Float16;
using f32x4 = __attribute__((ext_vector_type(4))) float;
using f32x2 = __attribute__((ext_vector_type(2))) float;

__device__ __forceinline__ float zlog_c(int t) {
  return (t < 128) ? (-1.0f + (float)t * 0.0078125f)
                   : ((float)(t - 128) * 0.015625f);
}
__device__ __forceinline__ float delta_c(int t) {
  if (t >= SC - 1) return 0.0f;
  return zlog_c(t + 1) - zlog_c(t);
}

__device__ __forceinline__ float fast_rcp(float x) { return __builtin_amdgcn_rcpf(x); }
__device__ __forceinline__ float fast_rsq(float x) { return __builtin_amdgcn_rsqf(x); }
__device__ __forceinline__ float exp10_f(float x) { return __expf(x * 2.30258509299f); }
__device__ __forceinline__ float softplus_f(float x) {
  return fmaxf(x, 0.0f) + __logf(1.0f + __expf(-fabsf(x)));
}

// packed FP32 (CDNA VOP3P): 2 f32 ops per instruction — MI355X's 157 TF fp32
// spec rate is exactly the packed rate (scalar v_fma_f32 is half, m07).
__device__ __forceinline__ f32x2 pk_fma2(f32x2 a, f32x2 b, f32x2 c) {
  f32x2 d;
  asm("v_pk_fma_f32 %0, %1, %2, %3" : "=v"(d) : "v"(a), "v"(b), "v"(c));
  return d;
}
__device__ __forceinline__ f32x2 pk_add2(f32x2 a, f32x2 b) {
  f32x2 d;
  asm("v_pk_add_f32 %0, %1, %2" : "=v"(d) : "v"(a), "v"(b));
  return d;
}

// fp16 helpers: pk2h = 1 HW instr (v_cvt_pkrtz_f16_f32); f2h = RTN scalar convert
__device__ __forceinline__ uint32_t pk2h(float a, float b) {
  auto p = __builtin_amdgcn_cvt_pkrtz(a, b);
  uint32_t u; __builtin_memcpy(&u, &p, 4); return u;
}
__device__ __forceinline__ unsigned short f2h(float f) {
  _Float16 h = (_Float16)f;
  unsigned short us; __builtin_memcpy(&us, &h, 2); return us;
}

__device__ __forceinline__ float4 ldsf4(const float* p) { return *(const float4*)p; }

// ---- shfl-based scans: FROZEN for the COARSE cdf path (R5 association). ----
// The cdf feeds searchsorted with u derived FROM the cdf; the whole coarse z
// path must stay bit-identical to the R5-passing kernel. Do NOT change.
__device__ __forceinline__ float wave_scan_mul(float v, int lane) {
#pragma unroll
  for (int d = 1; d < 64; d <<= 1) {
    float o = __shfl_up(v, d, 64);
    if (lane >= d) v *= o;
  }
  return v;
}
__device__ __forceinline__ float wave_scan_add(float v, int lane) {
#pragma unroll
  for (int d = 1; d < 64; d <<= 1) {
    float o = __shfl_up(v, d, 64);
    if (lane >= d) v += o;
  }
  return v;
}

// ---- DPP-based wave64 scans: VALU-only, no LDS/bpermute latency chains. ----
// Used ONLY on paths validated by passing outputs in R6/R7 runs:
// fine cumprod (output 1 passed) and output reductions (output 0 passed).
template <int CTRL, int RM>
__device__ __forceinline__ float dpp_upd(float old, float v) {
  return __int_as_float(__builtin_amdgcn_update_dpp(
      __float_as_int(old), __float_as_int(v), CTRL, RM, 0xf, false));
}
__device__ __forceinline__ float dpp_scan_mul(float v) {
  v *= dpp_upd<0x111, 0xf>(1.0f, v);
  v *= dpp_upd<0x112, 0xf>(1.0f, v);
  v *= dpp_upd<0x114, 0xf>(1.0f, v);
  v *= dpp_upd<0x118, 0xf>(1.0f, v);
  v *= dpp_upd<0x142, 0xa>(1.0f, v);   // rows 1,3 x= lane15/47
  v *= dpp_upd<0x143, 0xc>(1.0f, v);   // rows 2,3 x= lane31
  return v;
}
__device__ __forceinline__ float dpp_scan_add(float v) {
  v += dpp_upd<0x111, 0xf>(0.0f, v);
  v += dpp_upd<0x112, 0xf>(0.0f, v);
  v += dpp_upd<0x114, 0xf>(0.0f, v);
  v += dpp_upd<0x118, 0xf>(0.0f, v);
  v += dpp_upd<0x142, 0xa>(0.0f, v);
  v += dpp_upd<0x143, 0xc>(0.0f, v);
  return v;
}
template <int CTRL, int RM>
__device__ __forceinline__ f32x2 dpp_upd2(f32x2 v) {
  f32x2 r;
  r.x = dpp_upd<CTRL, RM>(0.0f, v.x);
  r.y = dpp_upd<CTRL, RM>(0.0f, v.y);
  return r;
}
__device__ __forceinline__ f32x2 dpp_scan_add2(f32x2 v) {
  v = pk_add2(v, dpp_upd2<0x111, 0xf>(v));
  v = pk_add2(v, dpp_upd2<0x112, 0xf>(v));
  v = pk_add2(v, dpp_upd2<0x114, 0xf>(v));
  v = pk_add2(v, dpp_upd2<0x118, 0xf>(v));
  v = pk_add2(v, dpp_upd2<0x142, 0xa>(v));
  v = pk_add2(v, dpp_upd2<0x143, 0xc>(v));
  return v;
}

// hidden-axis permutation for MFMA A-frags: frag0 row i -> hidden 8*(i>>2)+(i&3),
// frag1 row i -> +4. Then C rows (row = quad*4+reg) map to hidden 8*quad+reg(+4),
// so relu-packed C output lands register-direct as the NEXT MFMA's B-frag
// (k = quad*8 + j = true hidden index). No LDS round-trips.
__device__ __forceinline__ int hperm(int i, int ntf) {
  return 8 * (i >> 2) + (i & 3) + ntf * 4;
}

// JAX threefry2x32 with key = (0, 42)
__device__ __forceinline__ void threefry2x32_k42(uint32_t& x0, uint32_t& x1) {
  const uint32_t ks0 = 0u, ks1 = 42u;
  const uint32_t ks2 = ks0 ^ ks1 ^ 0x1BD11BDAu;
  const uint32_t ks[3] = {ks0, ks1, ks2};
  const int rot[2][4] = {{13, 15, 26, 6}, {17, 29, 16, 24}};
  x0 += ks[0];
  x1 += ks[1];
#pragma unroll
  for (int i = 0; i < 5; ++i) {
#pragma unroll
    for (int j = 0; j < 4; ++j) {
      x0 += x1;
      const int r = rot[i & 1][j];
      x1 = (x1 << r) | (x1 >> (32 - r));
      x1 ^= x0;
    }
    x0 += ks[(i + 1) % 3];
    x1 += ks[(i + 2) % 3] + (uint32_t)(i + 1);
  }
}

// ---- pre-pack kernel: weight image + K-inverse + fp16 Wc1 A-frags ----
__global__ __launch_bounds__(NT) void pack_weights(
    const float* __restrict__ K,
    const float* __restrict__ Wd1, const float* __restrict__ bd1,
    const float* __restrict__ Wd2, const float* __restrict__ bd2,
    const float* __restrict__ Wc1, const float* __restrict__ bc1,
    const float* __restrict__ Wc2, const float* __restrict__ bc2,
    float* __restrict__ wsf) {
  const int t = threadIdx.x;
  for (int i = t; i < 96; i += NT) wsf[WD1 + i] = Wd1[i];
  for (int i = t; i < 32; i += NT) { wsf[BD1 + i] = bd1[i]; wsf[WD2 + i] = Wd2[i]; }
  if (t == 0) {
    wsf[BD2] = bd2[0];
    wsf[BC2 + 0] = bc2[0]; wsf[BC2 + 1] = bc2[1]; wsf[BC2 + 2] = bc2[2];
    // K-inverse (identical float expressions to the former in-kernel version)
    const float k00 = K[0], k01 = K[1], k02 = K[2];
    const float k10 = K[3], k11 = K[4], k12 = K[5];
    const float k20 = K[6], k21 = K[7], k22 = K[8];
    const float det = k00 * (k11 * k22 - k12 * k21)
                    - k01 * (k10 * k22 - k12 * k20)
                    + k02 * (k10 * k21 - k11 * k20);
    const float id = 1.0f / det;
    wsf[KIV + 0] =  (k11 * k22 - k12 * k21) * id;
    wsf[KIV + 1] = -(k01 * k22 - k02 * k21) * id;
    wsf[KIV + 2] =  (k01 * k12 - k02 * k11) * id;
    wsf[KIV + 3] = -(k10 * k22 - k12 * k20) * id;
    wsf[KIV + 4] =  (k00 * k22 - k02 * k20) * id;
    wsf[KIV + 5] = -(k00 * k12 - k02 * k10) * id;
    wsf[KIV + 6] =  (k10 * k21 - k11 * k20) * id;
    wsf[KIV + 7] = -(k00 * k21 - k01 * k20) * id;
    wsf[KIV + 8] =  (k00 * k11 - k01 * k10) * id;
  }
  if (t < 32) {
    wsf[NV4 + t * 4 + 0] = bc1[t];
    wsf[NV4 + t * 4 + 1] = Wc1[32 * 32 + t];
    wsf[NV4 + t * 4 + 2] = Wc1[33 * 32 + t];
    wsf[NV4 + t * 4 + 3] = Wc1[34 * 32 + t];
  }
  // compact Wc2 fp16 A-frags for MFMA2 (16x16x32): A[m=channel][k=n]
  if (t < 12) {
    const int m = t % 3, q = t / 3;
    uint32_t hw[4];
#pragma unroll
    for (int j2 = 0; j2 < 4; ++j2) {
      const int k0 = q * 8 + j2 * 2;
      hw[j2] = (uint32_t)f2h(Wc2[k0 * 3 + m])
             | ((uint32_t)f2h(Wc2[(k0 + 1) * 3 + m]) << 16);
    }
    ((uint4*)(wsf + W24))[t] = make_uint4(hw[0], hw[1], hw[2], hw[3]);
  }
  // Wc1[0:32][:] fp16 A-frags (hidden-permuted): frag[lane*2 + nt]
  if (t < 64) {
    const int q_s = t >> 4;
    const int i = t & 15;
    uint4* frag = (uint4*)((char*)wsf + WS_FRAG_OFF);
#pragma unroll
    for (int nt = 0; nt < 2; ++nt) {
      const int n_s = hperm(i, nt);
      uint32_t hw[4];
#pragma unroll
      for (int j2 = 0; j2 < 4; ++j2) {
        const int k = q_s * 8 + j2 * 2;
        hw[j2] = (uint32_t)f2h(Wc1[k * 32 + n_s])
               | ((uint32_t)f2h(Wc1[(k + 1) * 32 + n_s]) << 16);
      }
      frag[t * 2 + nt] = make_uint4(hw[0], hw[1], hw[2], hw[3]);
    }
  }
}

template <bool USE_WS>
__global__ __launch_bounds__(NT, 8) void nerf_fwd(
    const float* __restrict__ hh, const float* __restrict__ ww,
    const float* __restrict__ K, const float* __restrict__ E,
    const float* __restrict__ bg,
    const float* __restrict__ Wd1, const float* __restrict__ bd1,
    const float* __restrict__ Wd2, const float* __restrict__ bd2,
    const float* __restrict__ Wc1, const float* __restrict__ bc1,
    const float* __restrict__ Wc2, const float* __restrict__ bc2,
    const float* __restrict__ wsf,
    float* __restrict__ out, int n_rays) {
  const int ray = blockIdx.x;
  const int t = threadIdx.x;
  const int lane = t & 63;
  const int wv = t >> 6;   // 0 or 1
  const int quad = lane >> 4;
  const int m15 = lane & 15;

  __shared__ __align__(16) float sw[SWTOT];
  __shared__ __align__(16) float s_A[32];
  __shared__ __align__(16) float s_B[32];
  // phase-union: coarse {s_w[192], s_cdf[192]} then fine {s_mm[128], s_sig[128], s_rgb[512]}
  __shared__ __align__(16) unsigned char u_buf[3072];
  float*    const s_w   = (float*)u_buf;                 // coarse
  float*    const s_cdf = (float*)(u_buf + 768);         // coarse
  uint32_t* const s_mm  = (uint32_t*)u_buf;              // fine: packed (ms,msz) fp16
  float*    const s_sig = (float*)(u_buf + 512);         // fine: sigma pre-softplus/bias
  float*    const s_rgb = (float*)(u_buf + 1024);        // fine: raw rgb logits (RGBS stride)
  __shared__ float s_zlf[SF];
  __shared__ float s_tot[8];
  __shared__ float s_red[16];
  float* const s_dv = sw;   // overlay on dead WD1 region (never read after staging)

  // ---- stage weight image into LDS ----
  if constexpr (USE_WS) {
    const float4* wsrc = (const float4*)wsf;
    float4* sdst = (float4*)sw;
    for (int i = t; i < SWTOT / 4; i += NT) sdst[i] = wsrc[i];
  } else {
    for (int i = t; i < 96; i += NT) sw[WD1 + i] = Wd1[i];
    for (int i = t; i < 32; i += NT) { sw[BD1 + i] = bd1[i]; sw[WD2 + i] = Wd2[i]; }
    if (t == 0) {
      sw[BD2] = bd2[0];
      sw[BC2 + 0] = bc2[0]; sw[BC2 + 1] = bc2[1]; sw[BC2 + 2] = bc2[2];
    }
    if (t < 32) {
      sw[NV4 + t * 4 + 0] = bc1[t];
      sw[NV4 + t * 4 + 1] = Wc1[32 * 32 + t];
      sw[NV4 + t * 4 + 2] = Wc1[33 * 32 + t];
      sw[NV4 + t * 4 + 3] = Wc1[34 * 32 + t];
    }
    if (t < 12) {
      const int m = t % 3, q = t / 3;
      uint32_t hw[4];
#pragma unroll
      for (int j2 = 0; j2 < 4; ++j2) {
        const int k0 = q * 8 + j2 * 2;
        hw[j2] = (uint32_t)f2h(Wc2[k0 * 3 + m])
               | ((uint32_t)f2h(Wc2[(k0 + 1) * 3 + m]) << 16);
      }
      ((uint4*)(sw + W24))[t] = make_uint4(hw[0], hw[1], hw[2], hw[3]);
    }
  }

  // ---- ray setup ----
  float i00, i01, i02, i10, i11, i12, i20, i21, i22;
  if constexpr (USE_WS) {
    // uniform address -> scalar loads, zero VALU
    i00 = wsf[KIV + 0]; i01 = wsf[KIV + 1]; i02 = wsf[KIV + 2];
    i10 = wsf[KIV + 3]; i11 = wsf[KIV + 4]; i12 = wsf[KIV + 5];
    i20 = wsf[KIV + 6]; i21 = wsf[KIV + 7]; i22 = wsf[KIV + 8];
  } else {
    const float k00 = K[0], k01 = K[1], k02 = K[2];
    const float k10 = K[3], k11 = K[4], k12 = K[5];
    const float k20 = K[6], k21 = K[7], k22 = K[8];
    const float det = k00 * (k11 * k22 - k12 * k21)
                    - k01 * (k10 * k22 - k12 * k20)
                    + k02 * (k10 * k21 - k11 * k20);
    const float id = 1.0f / det;
    i00 =  (k11 * k22 - k12 * k21) * id;
    i01 = -(k01 * k22 - k02 * k21) * id;
    i02 =  (k01 * k12 - k02 * k11) * id;
    i10 = -(k10 * k22 - k12 * k20) * id;
    i11 =  (k00 * k22 - k02 * k20) * id;
    i12 = -(k00 * k12 - k02 * k10) * id;
    i20 =  (k10 * k21 - k11 * k20) * id;
    i21 = -(k00 * k21 - k01 * k20) * id;
    i22 =  (k00 * k11 - k01 * k10) * id;
  }

  const float dwx = ww[ray] + 0.5f;
  const float dwy = hh[ray] + 0.5f;
  const float cx = i00 * dwx + i01 * dwy + i02;
  const float cy = i10 * dwx + i11 * dwy + i12;
  const float cz = i20 * dwx + i21 * dwy + i22;
  const float* Er = E + (size_t)ray * 16;
  const float ox = Er[3], oy = Er[7], oz = Er[11];
  const float dx = Er[0] * cx + Er[1] * cy + Er[2] * cz;
  const float dy = Er[4] * cx + Er[5] * cy + Er[6] * cz;
  const float dz = Er[8] * cx + Er[9] * cy + Er[10] * cz;
  const float dd = dx * dx + dy * dy + dz * dz;
  const float inv_nrm = fast_rsq(dd);
  const float ndx = dx * inv_nrm, ndy = dy * inv_nrm, ndz = dz * inv_nrm;
  // quadratic-expansion constants for dist^2 = |o + d z|^2
  const float oo  = ox * ox + oy * oy + oz * oz;
  const float od2 = 2.0f * (ox * dx + oy * dy + oz * dz);

  // A_n = o . Wd1[:,n], B_n = d . Wd1[:,n]  (per-ray, 32 threads, reads global Wd1)
  if (t < 32) {
    const float w0 = Wd1[t], w1 = Wd1[32 + t], w2 = Wd1[64 + t];
    s_A[t] = ox * w0 + oy * w1 + oz * w2;
    s_B[t] = dx * w0 + dy * w1 + dz * w2;
  }

  __syncthreads();   // weights + A/B staged

  // per-ray dv table: dv_n = bc1[n] + nd . Wc1[32:35][:,n]  (overlays dead WD1 region)
  if (t < 32) {
    const float4 nv = ldsf4(sw + NV4 + t * 4);
    s_dv[t] = nv.x + ndx * nv.y + ndy * nv.z + ndz * nv.w;
  }

  // ---- coarse pass (f32, packed): e0 = t (all); e1 = 128+t (wave 0, fused) ----
  // EXACT R5 form: this path determines the cdf / search indices (sampling
  // positions). Bit-frozen — no folds, no reassociation.
  const float bd2v = sw[BD2];
  float a0, v0, a1e = 0.0f, v1e = 1.0f;
  {
    float ms0, msz0, ms1 = 0.f, msz1 = 0.f;
    {
      const float z = exp10_f(zlog_c(t));
      const float d2 = fmaf(z, fmaf(z, dd, od2), oo);
      const float r = fast_rsq(fmaxf(d2, 1.0f));
      ms0 = (2.0f - r) * r;
      msz0 = ms0 * z;
    }
    if (wv == 0) {
      const float z = exp10_f((float)t * 0.015625f);   // zlog_c(128+t)
      const float d2 = fmaf(z, fmaf(z, dd, od2), oo);
      const float r = fast_rsq(fmaxf(d2, 1.0f));
      ms1 = (2.0f - r) * r;
      msz1 = ms1 * z;
    }
    const f32x2 msp0 = {ms0, ms0}, mszp0 = {msz0, msz0};
    const f32x2 msp1 = {ms1, ms1}, mszp1 = {msz1, msz1};
    f32x2 ac0a = {0.f, 0.f}, ac0b = {0.f, 0.f};
    f32x2 ac1a = {0.f, 0.f}, ac1b = {0.f, 0.f};
    if (wv == 0) {  // wave-uniform branch: fused 2-sample loop (coeffs loaded once)
#pragma unroll 2
      for (int c = 0; c < 8; ++c) {
        const int k4 = c * 4;
        const float4 A  = ldsf4(s_A + k4);
        const float4 B  = ldsf4(s_B + k4);
        const float4 b  = ldsf4(sw + BD1 + k4);
        const float4 wd = ldsf4(sw + WD2 + k4);
        const f32x2 Axy = {A.x, A.y}, Azw = {A.z, A.w};
        const f32x2 Bxy = {B.x, B.y}, Bzw = {B.z, B.w};
        const f32x2 bxy = {b.x, b.y}, bzw = {b.z, b.w};
        const f32x2 wxy = {wd.x, wd.y}, wzw = {wd.z, wd.w};
        f32x2 p;
        p = pk_fma2(mszp0, Bxy, pk_fma2(msp0, Axy, bxy));
        p.x = fmaxf(p.x, 0.f); p.y = fmaxf(p.y, 0.f);
        ac0a = pk_fma2(p, wxy, ac0a);
        p = pk_fma2(mszp0, Bzw, pk_fma2(msp0, Azw, bzw));
        p.x = fmaxf(p.x, 0.f); p.y = fmaxf(p.y, 0.f);
        ac0b = pk_fma2(p, wzw, ac0b);
        p = pk_fma2(mszp1, Bxy, pk_fma2(msp1, Axy, bxy));
        p.x = fmaxf(p.x, 0.f); p.y = fmaxf(p.y, 0.f);
        ac1a = pk_fma2(p, wxy, ac1a);
        p = pk_fma2(mszp1, Bzw, pk_fma2(msp1, Azw, bzw));
        p.x = fmaxf(p.x, 0.f); p.y = fmaxf(p.y, 0.f);
        ac1b = pk_fma2(p, wzw, ac1b);
      }
    } else {
#pragma unroll 2
      for (int c = 0; c < 8; ++c) {
        const int k4 = c * 4;
        const float4 A  = ldsf4(s_A + k4);
        const float4 B  = ldsf4(s_B + k4);
        const float4 b  = ldsf4(sw + BD1 + k4);
        const float4 wd = ldsf4(sw + WD2 + k4);
        const f32x2 Axy = {A.x, A.y}, Azw = {A.z, A.w};
        const f32x2 Bxy = {B.x, B.y}, Bzw = {B.z, B.w};
        const f32x2 bxy = {b.x, b.y}, bzw = {b.z, b.w};
        const f32x2 wxy = {wd.x, wd.y}, wzw = {wd.z, wd.w};
        f32x2 p;
        p = pk_fma2(mszp0, Bxy, pk_fma2(msp0, Axy, bxy));
        p.x = fmaxf(p.x, 0.f); p.y = fmaxf(p.y, 0.f);
        ac0a = pk_fma2(p, wxy, ac0a);
        p = pk_fma2(mszp0, Bzw, pk_fma2(msp0, Azw, bzw));
        p.x = fmaxf(p.x, 0.f); p.y = fmaxf(p.y, 0.f);
        ac0b = pk_fma2(p, wzw, ac0b);
      }
    }
    const float acc0 = bd2v + ((ac0a.x + ac0a.y) + (ac0b.x + ac0b.y));
    v0 = __expf(-softplus_f(acc0) * delta_c(t));
    a0 = 1.0f - v0;
    if (wv == 0) {
      const float acc1 = bd2v + ((ac1a.x + ac1a.y) + (ac1b.x + ac1b.y));
      v1e = __expf(-softplus_f(acc1) * delta_c(128 + t));
      a1e = 1.0f - v1e;
    }
  }

  // parallel cumprod of (1-alpha) — shfl scans (R5 association, FROZEN)
  float i0 = wave_scan_mul(v0, lane);
  float i1 = 1.0f;
  if (wv == 0) i1 = wave_scan_mul(v1e, lane);
  if (lane == 63) s_tot[wv] = i0;
  if (wv == 0 && lane == 63) s_tot[2] = i1;
  __syncthreads();
  {
    const float preC1 = s_tot[0];
    const float preC2 = s_tot[0] * s_tot[1];
    float e0x = __shfl_up(i0, 1, 64); if (lane == 0) e0x = 1.0f;
    s_w[t] = a0 * e0x * (wv ? preC1 : 1.0f);
    if (wv == 0) {
      float e1x = __shfl_up(i1, 1, 64); if (lane == 0) e1x = 1.0f;
      s_w[128 + t] = a1e * e1x * preC2;
    }
  }
  __syncthreads();

  // reweight (EXACT R5 form)
  float wre0, wre1 = 0.0f;
  {
    const float wm = (t > 0) ? s_w[t - 1] : 0.0f;
    const float w0 = s_w[t];
    const float wp = s_w[t + 1];
    wre0 = 0.5f * (fmaxf(wm, w0) + fmaxf(w0, wp)) + (0.02f / 192.0f);
    wre0 *= (t < 128) ? (128.0f / 192.0f) : (64.0f / 192.0f);
  }
  if (wv == 0) {
    const int e = 128 + t;
    const float wm = s_w[e - 1];
    const float w0 = s_w[e];
    const float wp = (e < SC - 1) ? s_w[e + 1] : 0.0f;
    wre1 = 0.5f * (fmaxf(wm, w0) + fmaxf(w0, wp)) + (0.02f / 192.0f);
    wre1 *= (64.0f / 192.0f);
  }

  // parallel cumsum -> normalized CDF — shfl scans (R5 association, FROZEN)
  float s0 = wave_scan_add(wre0, lane);
  float s1 = 0.0f;
  if (wv == 0) s1 = wave_scan_add(wre1, lane);
  if (lane == 63) s_tot[4 + wv] = s0;
  if (wv == 0 && lane == 63) s_tot[6] = s1;
  __syncthreads();
  {
    const float T0 = s_tot[4], T1 = s_tot[5], T2 = s_tot[6];
    const float inv_total = fast_rcp(T0 + T1 + T2);
    s_cdf[t] = (s0 + (wv ? T0 : 0.0f)) * inv_total;
    if (wv == 0) s_cdf[128 + t] = (s1 + T0 + T1) * inv_total;
  }
  __syncthreads();

  // ---- importance sampling (EXACT R5 form: plain binary search) ----
  float zlf, zf;
  {
    const uint32_t total = (uint32_t)n_rays * 128u;
    const uint32_t halfc = total >> 1;
    const uint32_t j = (uint32_t)ray * 128u + (uint32_t)t;
    uint32_t x0, x1;
    const bool first = (j < halfc);
    if (first) { x0 = j; x1 = j + halfc; } else { x0 = j - halfc; x1 = j; }
    threefry2x32_k42(x0, x1);
    const uint32_t bits = first ? x0 : x1;
    const float fr = __uint_as_float((bits >> 9) | 0x3f800000u) - 1.0f;

    float u = (float)t * 0.0078125f + fr * 0.0078125f;
    u = u * (s_cdf[190] - s_cdf[1]) + s_cdf[1];

    int lo = 0, hi = 189;
    while (lo < hi) {
      const int mid = (lo + hi) >> 1;
      if (s_cdf[1 + mid] <= u) lo = mid + 1; else hi = mid;
    }
    const int inds = lo + 1;
    const float cb = s_cdf[inds - 1], ca = s_cdf[inds];
    const float tt = (u - cb) * fast_rcp(ca - cb);
    const float zb = 0.5f * (zlog_c(inds - 1) + zlog_c(inds));
    const float za = 0.5f * (zlog_c(inds) + zlog_c(inds + 1));
    zlf = zb + (za - zb) * tt;
    s_zlf[t] = zlf;
    zf = exp10_f(zlf);
  }
  __syncthreads();   // last s_cdf read — union area now free for s_mm/s_sig/s_rgb

  // ---- fine phase, pass 1: density via MFMA ----
  // input per sample = (ms, msz, 1); h = relu([A;B;b] @ (ms,msz,1)); sigma = wd.h
  // All LDS traffic below is same-wave (wave wv touches only samples wv*64..+63).
  {
    const float d2 = fmaf(zf, fmaf(zf, dd, od2), oo);
    const float r = fast_rsq(fmaxf(d2, 1.0f));
    const float msf = (2.0f - r) * r;
    s_mm[t] = pk2h(msf, msf * zf);
  }

  uint4 BhS0, BhS1, BhS2, BhS3;   // per-group packed h (fp16 B-frags), pass1 -> pass2
  {
    const bool q0 = (quad == 0);
    const int ma = hperm(m15, 0), mb = hperm(m15, 1);
    uint4 fa, fb, fd;
    fa.x = q0 ? pk2h(s_A[ma], s_B[ma]) : 0u;
    fa.y = q0 ? (uint32_t)f2h(sw[BD1 + ma]) : 0u;
    fa.z = 0u; fa.w = 0u;
    fb.x = q0 ? pk2h(s_A[mb], s_B[mb]) : 0u;
    fb.y = q0 ? (uint32_t)f2h(sw[BD1 + mb]) : 0u;
    fb.z = 0u; fb.w = 0u;
    const bool r0 = (m15 == 0);
    fd.x = r0 ? pk2h(sw[WD2 + quad * 8 + 0], sw[WD2 + quad * 8 + 1]) : 0u;
    fd.y = r0 ? pk2h(sw[WD2 + quad * 8 + 2], sw[WD2 + quad * 8 + 3]) : 0u;
    fd.z = r0 ? pk2h(sw[WD2 + quad * 8 + 4], sw[WD2 + quad * 8 + 5]) : 0u;
    fd.w = r0 ? pk2h(sw[WD2 + quad * 8 + 6], sw[WD2 + quad * 8 + 7]) : 0u;
    half8 Waug0, Waug1, WdF;
    __builtin_memcpy(&Waug0, &fa, 16);
    __builtin_memcpy(&Waug1, &fb, 16);
    __builtin_memcpy(&WdF, &fd, 16);

#pragma unroll
    for (int g = 0; g < 4; ++g) {
      const uint32_t mm = s_mm[wv * 64 + g * 16 + m15];
      uint4 bm;
      bm.x = (quad == 0) ? mm : 0u;
      bm.y = (quad == 0) ? 0x00003C00u : 0u;   // halves (1.0, 0)
      bm.z = 0u; bm.w = 0u;
      half8 Bms; __builtin_memcpy(&Bms, &bm, 16);

      f32x4 ad0 = {0.f, 0.f, 0.f, 0.f}, ad1 = {0.f, 0.f, 0.f, 0.f};
      ad0 = __builtin_amdgcn_mfma_f32_16x16x32_f16(Waug0, Bms, ad0, 0, 0, 0);
      ad1 = __builtin_amdgcn_mfma_f32_16x16x32_f16(Waug1, Bms, ad1, 0, 0, 0);

      uint4 bh;
      bh.x = pk2h(fmaxf(ad0[0], 0.0f), fmaxf(ad0[1], 0.0f));
      bh.y = pk2h(fmaxf(ad0[2], 0.0f), fmaxf(ad0[3], 0.0f));
      bh.z = pk2h(fmaxf(ad1[0], 0.0f), fmaxf(ad1[1], 0.0f));
      bh.w = pk2h(fmaxf(ad1[2], 0.0f), fmaxf(ad1[3], 0.0f));
      if (g == 0) BhS0 = bh; else if (g == 1) BhS1 = bh;
      else if (g == 2) BhS2 = bh; else BhS3 = bh;

      half8 Bh; __builtin_memcpy(&Bh, &bh, 16);
      f32x4 as = {0.f, 0.f, 0.f, 0.f};
      as = __builtin_amdgcn_mfma_f32_16x16x32_f16(WdF, Bh, as, 0, 0, 0);
      if (quad == 0) s_sig[wv * 64 + g * 16 + m15] = as[0];  // sigma pre-bias
    }
  }
  const float sigf = softplus_f(s_sig[t] + bd2v);   // same-wave read

  // ---- fine phase, pass 2: color via MFMA (register-direct chain) ----
  // Stores RAW rgb logits (pre-bias, pre-sigmoid); sigmoid applied at output
  // stage where all 64 lanes do exactly 3 (vs 12 under quad0 exec-mask here).
  {
    half8 Whi0, Whi1;
    if constexpr (USE_WS) {
      const uint4* frag = (const uint4*)((const char*)wsf + WS_FRAG_OFF);
      uint4 q0v = frag[lane * 2 + 0];
      uint4 q1v = frag[lane * 2 + 1];
      __builtin_memcpy(&Whi0, &q0v, 16);
      __builtin_memcpy(&Whi1, &q1v, 16);
    } else {
#pragma unroll
      for (int nt = 0; nt < 2; ++nt) {
        const int n_s = hperm(m15, nt);
        uint32_t hw[4];
#pragma unroll
        for (int j2 = 0; j2 < 4; ++j2) {
          const int k = quad * 8 + j2 * 2;
          hw[j2] = (uint32_t)f2h(Wc1[k * 32 + n_s])
                 | ((uint32_t)f2h(Wc1[(k + 1) * 32 + n_s]) << 16);
        }
        uint4 q = make_uint4(hw[0], hw[1], hw[2], hw[3]);
        if (nt == 0) __builtin_memcpy(&Whi0, &q, 16);
        else         __builtin_memcpy(&Whi1, &q, 16);
      }
    }
    const float4 dv0 = ldsf4(s_dv + quad * 8);       // hidden 8q..8q+3
    const float4 dv1 = ldsf4(s_dv + quad * 8 + 4);   // hidden 8q+4..8q+7
    uint4 qf = ((const uint4*)(sw + W24))[quad * 3 + (m15 < 3 ? m15 : 0)];
    if (m15 >= 3) qf = make_uint4(0u, 0u, 0u, 0u);
    half8 W2f; __builtin_memcpy(&W2f, &qf, 16);

#pragma unroll
    for (int g = 0; g < 4; ++g) {
      uint4 bh = (g == 0) ? BhS0 : (g == 1) ? BhS1 : (g == 2) ? BhS2 : BhS3;
      half8 Bh; __builtin_memcpy(&Bh, &bh, 16);

      f32x4 c0 = {0.f, 0.f, 0.f, 0.f}, c1 = {0.f, 0.f, 0.f, 0.f};
      c0 = __builtin_amdgcn_mfma_f32_16x16x32_f16(Whi0, Bh, c0, 0, 0, 0);
      c1 = __builtin_amdgcn_mfma_f32_16x16x32_f16(Whi1, Bh, c1, 0, 0, 0);

      uint4 bw;
      bw.x = pk2h(fmaxf(c0[0] + dv0.x, 0.0f), fmaxf(c0[1] + dv0.y, 0.0f));
      bw.y = pk2h(fmaxf(c0[2] + dv0.z, 0.0f), fmaxf(c0[3] + dv0.w, 0.0f));
      bw.z = pk2h(fmaxf(c1[0] + dv1.x, 0.0f), fmaxf(c1[1] + dv1.y, 0.0f));
      bw.w = pk2h(fmaxf(c1[2] + dv1.z, 0.0f), fmaxf(c1[3] + dv1.w, 0.0f));
      half8 Bav; __builtin_memcpy(&Bav, &bw, 16);

      f32x4 c2 = {0.f, 0.f, 0.f, 0.f};
      c2 = __builtin_amdgcn_mfma_f32_16x16x32_f16(W2f, Bav, c2, 0, 0, 0);
      if (quad == 0) {
        const int scol = wv * 64 + g * 16 + m15;
        *(f32x4*)(s_rgb + scol * RGBS) = c2;   // raw logits; c2[3] == 0
      }
    }
  }

  // ---- fine alpha + parallel cumprod over 128 ----
  // DPP scan here was validated end-to-end: output 1 (weights) passed in the
  // R6/R7 runs with this exact code.
  const float deltaf = (t < SF - 1) ? (s_zlf[t + 1] - zlf) : 0.0f;
  const float vf = __expf(-sigf * deltaf);
  const float af = 1.0f - vf;
  float fi = dpp_scan_mul(vf);
  if (lane == 63) s_tot[wv] = fi;
  __syncthreads();   // s_tot cross-wave (s_rgb reads below are same-wave)
  float efx = __shfl_up(fi, 1, 64); if (lane == 0) efx = 1.0f;
  const float wf = af * efx * (wv ? s_tot[0] : 1.0f);

  // ---- outputs ----
  float* o_img = out;
  float* o_w   = out + (size_t)n_rays * 3;
  float* o_z   = out + (size_t)n_rays * (3 + 128);
  float* o_inv = out + (size_t)n_rays * (3 + 256);

  o_w[(size_t)ray * 128 + t] = wf;
  o_z[(size_t)ray * 128 + t] = (zlf + 1.0f) * 0.5f;

  const float bc2x = sw[BC2 + 0], bc2y = sw[BC2 + 1], bc2z = sw[BC2 + 2];
  const float4 rgbv = ldsf4(s_rgb + t * RGBS);
  const float sr = fast_rcp(1.0f + __expf(-(rgbv.x + bc2x)));
  const float sg = fast_rcp(1.0f + __expf(-(rgbv.y + bc2y)));
  const float sb = fast_rcp(1.0f + __expf(-(rgbv.z + bc2z)));

  // 5-value wave reduction via DPP add-scan (total lands in lane 63).
  // Validated end-to-end: output 0 (image, incl. accw path) passed in R6/R7.
  f32x2 p01 = {wf * sr, wf * sg};
  f32x2 p23 = {wf * sb, wf};
  float r4 = wf * fast_rcp(zf);
  p01 = dpp_scan_add2(p01);
  p23 = dpp_scan_add2(p23);
  r4 = dpp_scan_add(r4);
  if (lane == 63) {
    float* p = &s_red[wv * 5];
    p[0] = p01.x; p[1] = p01.y; p[2] = p23.x; p[3] = p23.y; p[4] = r4;
  }
  __syncthreads();
  if (t == 0) {
    const float accw = s_red[3] + s_red[8];
    const float bgw = 1.0f - accw;
    o_img[(size_t)ray * 3 + 0] = (s_red[0] + s_red[5]) + bgw * bg[0];
    o_img[(size_t)ray * 3 + 1] = (s_red[1] + s_red[6]) + bgw * bg[1];
    o_img[(size_t)ray * 3 + 2] = (s_red[2] + s_red[7]) + bgw * bg[2];
    o_inv[ray] = s_red[4] + s_red[9];
  }
}

extern "C" void kernel_launch(void* const* d_in, const int* in_sizes, int n_in,
                              void* d_out, int out_size, void* d_ws, size_t ws_size,
                              hipStream_t stream) {
  const float* h   = (const float*)d_in[1];
  const float* w   = (const float*)d_in[2];
  const float* K   = (const float*)d_in[3];
  const float* E   = (const float*)d_in[4];
  const float* bg  = (const float*)d_in[5];
  const float* Wd1 = (const float*)d_in[6];
  const float* bd1 = (const float*)d_in[7];
  const float* Wd2 = (const float*)d_in[8];
  const float* bd2 = (const float*)d_in[9];
  const float* Wc1 = (const float*)d_in[10];
  const float* bc1 = (const float*)d_in[11];
  const float* Wc2 = (const float*)d_in[12];
  const float* bc2 = (const float*)d_in[13];
  const int n_rays = in_sizes[1];
  float* wsf = (float*)d_ws;

  if (ws_size >= WS_NEED) {
    pack_weights<<<1, NT, 0, stream>>>(K, Wd1, bd1, Wd2, bd2, Wc1, bc1, Wc2, bc2, wsf);
    nerf_fwd<true><<<n_rays, NT, 0, stream>>>(h, w, K, E, bg, Wd1, bd1, Wd2, bd2,
                                              Wc1, bc1, Wc2, bc2, wsf,
                                              (float*)d_out, n_rays);
  } else {
    nerf_fwd<false><<<n_rays, NT, 0, stream>>>(h, w, K, E, bg, Wd1, bd1, Wd2, bd2,
                                               Wc1, bc1, Wc2, bc2, nullptr,
                                               (float*)d_out, n_rays);
  }
}